// Round 1
// baseline (311.615 us; speedup 1.0000x reference)
//
#include <hip/hip_runtime.h>
#include <math.h>

// ---------------------------------------------------------------------------
// CurriculumLoss: l_count + t*(OT via Sinkhorn on 64x64 downsample) + t*TV
//
// Key numeric fact: K = exp(-M/0.05) with M = squared grid distance underflows
// to exactly 0 in f32 for M >= 8 (exp(-160) ~ 2.5e-70). Surviving taps:
//   M=0: 1.0          (center)
//   M=1: exp(-20)     (+-1,0),(0,+-1)
//   M=2: exp(-40)     (+-1,+-1)
//   M=4: exp(-80)     (+-2,0),(0,+-2)
//   M=5: exp(-100)    (+-2,+-1),(+-1,+-2)   [f32 denormal]
// So each dense matvec u@K is a 21-point stencil on the 64x64 grid.
// ---------------------------------------------------------------------------

#define PITCH 68              // 64 + 2 halo each side
#define PLDS  (PITCH * PITCH) // 4624 floats

#define KW1 2.0611536224385578e-09f  // exp(-20)
#define KW2 4.2483542552915889e-18f  // exp(-40)
#define KW4 1.8048513878454153e-35f  // exp(-80)
#define KW5 3.7200759760208360e-44f  // exp(-100), denormal
// K*M weights for the final einsum (center M=0 contributes nothing)
#define MW1 2.0611536224385578e-09f  // 1*exp(-20)
#define MW2 8.4967085105831778e-18f  // 2*exp(-40)
#define MW4 7.2194055513816612e-35f  // 4*exp(-80)
#define MW5 1.8600379880104180e-43f  // 5*exp(-100), denormal

// Load a 5-row x 8-col window (rows y-2..y+2, cols x0-2..x0+5) from a padded
// LDS field. wb = y*PITCH + x0 is 16B-aligned (PITCH%4==0, x0%4==0).
__device__ __forceinline__ void load_win(const float* s, int wb, float w[5][8]) {
#pragma unroll
  for (int r = 0; r < 5; ++r) {
    const float4 A = *(const float4*)(s + wb + r * PITCH);
    const float4 B = *(const float4*)(s + wb + r * PITCH + 4);
    w[r][0] = A.x; w[r][1] = A.y; w[r][2] = A.z; w[r][3] = A.w;
    w[r][4] = B.x; w[r][5] = B.y; w[r][6] = B.z; w[r][7] = B.w;
  }
}

// 21-tap K stencil at pixel j (j in 0..3 within the 8-wide window)
__device__ __forceinline__ float stK(const float w[5][8], int j) {
  return w[2][j + 2]
       + KW1 * ((w[2][j + 1] + w[2][j + 3]) + (w[1][j + 2] + w[3][j + 2]))
       + KW2 * ((w[1][j + 1] + w[1][j + 3]) + (w[3][j + 1] + w[3][j + 3]))
       + KW4 * ((w[2][j] + w[2][j + 4]) + (w[0][j + 2] + w[4][j + 2]))
       + KW5 * (((w[1][j] + w[1][j + 4]) + (w[3][j] + w[3][j + 4]))
              + ((w[0][j + 1] + w[0][j + 3]) + (w[4][j + 1] + w[4][j + 3])));
}

// 20-tap K*M stencil (center weight is 0)
__device__ __forceinline__ float stM(const float w[5][8], int j) {
  return MW1 * ((w[2][j + 1] + w[2][j + 3]) + (w[1][j + 2] + w[3][j + 2]))
       + MW2 * ((w[1][j + 1] + w[1][j + 3]) + (w[3][j + 1] + w[3][j + 3]))
       + MW4 * ((w[2][j] + w[2][j + 4]) + (w[0][j + 2] + w[4][j + 2]))
       + MW5 * (((w[1][j] + w[1][j + 4]) + (w[3][j] + w[3][j + 4]))
              + ((w[0][j + 1] + w[0][j + 3]) + (w[4][j + 1] + w[4][j + 3])));
}

// One block per batch image. Fuses: 4x4 avg-pool, count sums, normalize,
// 50 Sinkhorn iterations (u,v in zero-halo-padded LDS), cost einsum.
__global__ __launch_bounds__(1024) void sinkhorn_kernel(
    const float* __restrict__ pred, const float* __restrict__ gt,
    float* __restrict__ pc, float* __restrict__ gc, float* __restrict__ cost) {
  __shared__ float su[PLDS];
  __shared__ float sv[PLDS];
  __shared__ float rbuf[64];

  const int b  = blockIdx.x;
  const int t  = threadIdx.x;
  const int y  = t >> 4;          // ds row 0..63
  const int x0 = (t & 15) << 2;   // ds col start 0..60

  // zero both fields including halos
  for (int i = t; i < PLDS; i += 1024) { su[i] = 0.0f; sv[i] = 0.0f; }

  // downsample: each thread owns 4 consecutive ds pixels in row y
  const float* pb = pred + b * 65536;
  const float* gb = gt   + b * 65536;
  float pdv[4], gdv[4];
  float spraw = 0.f, sgraw = 0.f, spd = 0.f, sgd = 0.f;
#pragma unroll
  for (int j = 0; j < 4; ++j) {
    const float* p0 = pb + (y * 4) * 256 + (x0 + j) * 4;
    const float* g0 = gb + (y * 4) * 256 + (x0 + j) * 4;
    float s = 0.f, s2 = 0.f;
#pragma unroll
    for (int r = 0; r < 4; ++r) {
      const float4 q = *(const float4*)(p0 + r * 256);
      s  += (q.x + q.y) + (q.z + q.w);
      const float4 g = *(const float4*)(g0 + r * 256);
      s2 += (g.x + g.y) + (g.z + g.w);
    }
    spraw += s; sgraw += s2;
    const float pm = fmaxf(s  * 0.0625f, 0.f);   // relu(avg-pool)
    const float gm = fmaxf(s2 * 0.0625f, 0.f);
    pdv[j] = pm; gdv[j] = gm;
    spd += pm; sgd += gm;
  }

  __syncthreads();  // zero-fill complete
  const int ubase = (y + 2) * PITCH + (x0 + 2);
  sv[ubase + 0] = 1.f; sv[ubase + 1] = 1.f;
  sv[ubase + 2] = 1.f; sv[ubase + 3] = 1.f;   // v init = ones (interior)

  // block-reduce the 4 sums
  float v0 = spraw, v1 = sgraw, v2 = spd, v3 = sgd;
#pragma unroll
  for (int o = 32; o > 0; o >>= 1) {
    v0 += __shfl_down(v0, o);
    v1 += __shfl_down(v1, o);
    v2 += __shfl_down(v2, o);
    v3 += __shfl_down(v3, o);
  }
  if ((t & 63) == 0) {
    const int w = t >> 6;
    rbuf[w * 4 + 0] = v0; rbuf[w * 4 + 1] = v1;
    rbuf[w * 4 + 2] = v2; rbuf[w * 4 + 3] = v3;
  }
  __syncthreads();
  if (t == 0) {
    float a0 = 0, a1 = 0, a2 = 0, a3 = 0;
    for (int w = 0; w < 16; ++w) {
      a0 += rbuf[w * 4]; a1 += rbuf[w * 4 + 1];
      a2 += rbuf[w * 4 + 2]; a3 += rbuf[w * 4 + 3];
    }
    pc[b] = a0; gc[b] = a1;
    rbuf[0] = a0; rbuf[1] = a1; rbuf[2] = a2; rbuf[3] = a3;
  }
  __syncthreads();
  const float Sp = rbuf[2], Sg = rbuf[3];

  float av[4], bv[4];
#pragma unroll
  for (int j = 0; j < 4; ++j) {
    av[j] = (Sp > 0.f) ? (pdv[j] / Sp) : (1.f / 4096.f);
    bv[j] = (Sg > 0.f) ? (gdv[j] / Sg) : (1.f / 4096.f);
  }

  const int wb = y * PITCH + x0;   // window base: (row y-2, col x0-2) padded
  float un[4] = {0.f, 0.f, 0.f, 0.f};

#pragma unroll 1
  for (int it = 0; it < 50; ++it) {
    float w[5][8];
    load_win(sv, wb, w);           // u = a / (K v)
#pragma unroll
    for (int j = 0; j < 4; ++j) un[j] = av[j] / stK(w, j);
    *(float2*)&su[ubase]     = make_float2(un[0], un[1]);
    *(float2*)&su[ubase + 2] = make_float2(un[2], un[3]);
    __syncthreads();
    load_win(su, wb, w);           // v = b / (K u), K symmetric
    float vn[4];
#pragma unroll
    for (int j = 0; j < 4; ++j) vn[j] = bv[j] / stK(w, j);
    *(float2*)&sv[ubase]     = make_float2(vn[0], vn[1]);
    *(float2*)&sv[ubase + 2] = make_float2(vn[2], vn[3]);
    __syncthreads();
  }

  // cost_b = sum_i u_i * ((K.M) v)_i
  float c = 0.f;
  {
    float w[5][8];
    load_win(sv, wb, w);
#pragma unroll
    for (int j = 0; j < 4; ++j) c += un[j] * stM(w, j);
  }
#pragma unroll
  for (int o = 32; o > 0; o >>= 1) c += __shfl_down(c, o);
  if ((t & 63) == 0) rbuf[t >> 6] = c;
  __syncthreads();
  if (t == 0) {
    float s = 0.f;
    for (int w = 0; w < 16; ++w) s += rbuf[w];
    cost[b] = s;
  }
}

// TV partial sums: 256 blocks x 256 threads, per-block partials (no atomics)
__global__ __launch_bounds__(256) void tv_kernel(const float* __restrict__ pred,
                                                 float* __restrict__ tvx,
                                                 float* __restrict__ tvy) {
  __shared__ float rb[8];
  const int t = threadIdx.x;
  const int gid = blockIdx.x * 256 + t;  // position within one 256x256 image
  const int yy = gid >> 8, xx = gid & 255;
  float sx = 0.f, sy = 0.f;
#pragma unroll 1
  for (int k = 0; k < 16; ++k) {         // k = batch index
    const int idx = k * 65536 + gid;
    const float p = pred[idx];
    if (xx < 255) sx += fabsf(pred[idx + 1] - p);
    if (yy < 255) sy += fabsf(pred[idx + 256] - p);
  }
#pragma unroll
  for (int o = 32; o > 0; o >>= 1) { sx += __shfl_down(sx, o); sy += __shfl_down(sy, o); }
  if ((t & 63) == 0) { rb[(t >> 6) * 2] = sx; rb[(t >> 6) * 2 + 1] = sy; }
  __syncthreads();
  if (t == 0) {
    for (int w = 1; w < 4; ++w) { sx += rb[w * 2]; sy += rb[w * 2 + 1]; }
    tvx[blockIdx.x] = sx; tvy[blockIdx.x] = sy;
  }
}

__global__ __launch_bounds__(256) void finalize_kernel(
    const float* __restrict__ pc, const float* __restrict__ gc,
    const float* __restrict__ cost, const float* __restrict__ tvx,
    const float* __restrict__ tvy, const int* __restrict__ epoch,
    const int* __restrict__ max_epoch, float* __restrict__ out) {
  __shared__ float rb[8];
  const int t = threadIdx.x;
  float sx = tvx[t], sy = tvy[t];
#pragma unroll
  for (int o = 32; o > 0; o >>= 1) { sx += __shfl_down(sx, o); sy += __shfl_down(sy, o); }
  if ((t & 63) == 0) { rb[(t >> 6) * 2] = sx; rb[(t >> 6) * 2 + 1] = sy; }
  __syncthreads();
  if (t == 0) {
    for (int w = 1; w < 4; ++w) { sx += rb[w * 2]; sy += rb[w * 2 + 1]; }
    float lc = 0.f, lot = 0.f;
    for (int b = 0; b < 16; ++b) { lc += fabsf(pc[b] - gc[b]); lot += cost[b]; }
    lc *= (1.f / 16.f); lot *= (1.f / 16.f);
    const float ltv = sx / (16.f * 256.f * 255.f) + sy / (16.f * 255.f * 256.f);
    int me = max_epoch[0]; if (me < 1) me = 1;
    const float tt = (float)epoch[0] / (float)me;
    out[0] = lc + tt * lot + tt * ltv;   // LAMBDA_OT = LAMBDA_TV = 1
  }
}

extern "C" void kernel_launch(void* const* d_in, const int* in_sizes, int n_in,
                              void* d_out, int out_size, void* d_ws, size_t ws_size,
                              hipStream_t stream) {
  const float* pred  = (const float*)d_in[0];
  const float* gt    = (const float*)d_in[1];
  const int* epoch   = (const int*)d_in[2];
  const int* max_ep  = (const int*)d_in[3];
  float* out = (float*)d_out;

  // workspace layout (floats): pc[16] gc[16] cost[16] tvx[256] tvy[256]
  float* ws   = (float*)d_ws;
  float* pc   = ws;
  float* gc   = ws + 16;
  float* cost = ws + 32;
  float* tvx  = ws + 48;
  float* tvy  = ws + 304;

  tv_kernel<<<dim3(256), dim3(256), 0, stream>>>(pred, tvx, tvy);
  sinkhorn_kernel<<<dim3(16), dim3(1024), 0, stream>>>(pred, gt, pc, gc, cost);
  finalize_kernel<<<dim3(1), dim3(256), 0, stream>>>(pc, gc, cost, tvx, tvy,
                                                     epoch, max_ep, out);
}

// Round 2
// 165.630 us; speedup vs baseline: 1.8814x; 1.8814x over previous
//
#include <hip/hip_runtime.h>
#include <math.h>

// ---------------------------------------------------------------------------
// CurriculumLoss: l_count + t*(OT via Sinkhorn on 64x64 downsample) + t*TV
//
// K = exp(-M/0.05) underflows to 0 in f32 for M >= 8. Surviving taps:
//   M=0: 1, M=1: e^-20, M=2: e^-40, M=4: e^-80, M=5: e^-100.
// The M=4/5 taps (<= 1.8e-35) are invisible in f32 relative to the center
// unless distance-2 ratios exceed ~1e27; Sinkhorn's own w1-coupling clamps
// neighbor ratios to ~1/w1 = 5e8, so distance-2 ratios <= ~2.5e17 -> dropped
// taps contribute <= ~1e-17 relative. We keep the 9-tap kernel, which is
// EXACTLY separable: (1, e^-20) (x) (1, e^-20), corner = e^-40 = reference's
// M=2 weight. K.M similarly: edges e^-20, corners 2e^-40.
//
// Layout: fields in LDS, 2-halo, pitch 68 (zero halos handled for free, all
// window reads are two aligned ds_read_b128 per row). 256 active threads own
// 4x4 tiles; separable stencil in registers; rcp instead of fdiv.
// ---------------------------------------------------------------------------

#define PITCH 68
#define PLDS  (PITCH * PITCH)        // 4624
#define KW1 2.0611536224385578e-09f  // exp(-20)
#define MW2 8.4967085105831778e-18f  // 2*exp(-40)

// One half-iteration for a 4x4 tile: out = cf * rcp(K_9tap * src-field),
// written back to dst interior. rdb = storage offset of (field row y0-1,
// storage col x0); wbs = storage offset of (field row y0, field col x0).
__device__ __forceinline__ void half_iter(const float* __restrict__ src,
                                          float* __restrict__ dst,
                                          const float cf[4][4],
                                          int rdb, int wbs, float out[4][4]) {
  float w[6][8];
#pragma unroll
  for (int r = 0; r < 6; ++r) {
    const float4 A = *(const float4*)(src + rdb + r * PITCH);
    const float4 B = *(const float4*)(src + rdb + r * PITCH + 4);
    w[r][0] = A.x; w[r][1] = A.y; w[r][2] = A.z; w[r][3] = A.w;
    w[r][4] = B.x; w[r][5] = B.y; w[r][6] = B.z; w[r][7] = B.w;
  }
  float h[6][4];  // horizontal 3-tap
#pragma unroll
  for (int r = 0; r < 6; ++r)
#pragma unroll
    for (int j = 0; j < 4; ++j)
      h[r][j] = fmaf(KW1, w[r][j + 1] + w[r][j + 3], w[r][j + 2]);
#pragma unroll
  for (int i = 0; i < 4; ++i) {
#pragma unroll
    for (int j = 0; j < 4; ++j) {
      const float s = fmaf(KW1, h[i][j] + h[i + 2][j], h[i + 1][j]);
      out[i][j] = cf[i][j] * __builtin_amdgcn_rcpf(s);
    }
    *(float2*)(dst + wbs + i * PITCH)     = make_float2(out[i][0], out[i][1]);
    *(float2*)(dst + wbs + i * PITCH + 2) = make_float2(out[i][2], out[i][3]);
  }
}

// ws layout (floats): pc[0..16) gc[16..32) cost[32..48) tvx[48..64) tvy[64..80)
__global__ __launch_bounds__(1024) void fused_kernel(
    const float* __restrict__ pred, const float* __restrict__ gt,
    float* __restrict__ ws) {
  __shared__ float su[PLDS];
  __shared__ float sv[PLDS];
  __shared__ float sa[4096];
  __shared__ float sb[4096];
  __shared__ float rbuf[96];

  const int b = blockIdx.x;
  const int t = threadIdx.x;

  // zero both fields including halos (interior overwritten later)
  for (int i = t; i < PLDS; i += 1024) { su[i] = 0.f; sv[i] = 0.f; }

  // ---- pooling + count sums + TV (all 1024 threads) ----
  const int py  = t >> 4;          // ds row 0..63
  const int px0 = (t & 15) << 2;   // ds col 0..60
  const int C0  = px0 << 2;        // source col base (owns 16 cols)
  const float* pb = pred + b * 65536;
  const float* gb = gt   + b * 65536;
  const int rowbase = (py * 4) * 256;

  float pdv[4], gdv[4], prevw[4];
  float spraw = 0.f, sgraw = 0.f, spd = 0.f, sgd = 0.f, sx = 0.f, sy = 0.f;
#pragma unroll
  for (int j = 0; j < 4; ++j) {
    const float* p0 = pb + rowbase + C0 + 4 * j;
    const float* g0 = gb + rowbase + C0 + 4 * j;
    float4 q[4];
    float s = 0.f, s2 = 0.f;
#pragma unroll
    for (int r = 0; r < 4; ++r) {
      q[r] = *(const float4*)(p0 + r * 256);
      s += (q[r].x + q[r].y) + (q[r].z + q[r].w);
      const float4 g = *(const float4*)(g0 + r * 256);
      s2 += (g.x + g.y) + (g.z + g.w);
    }
#pragma unroll
    for (int r = 0; r < 4; ++r) {  // dx: within quad + cross-quad
      sx += fabsf(q[r].y - q[r].x) + fabsf(q[r].z - q[r].y) + fabsf(q[r].w - q[r].z);
      if (j > 0) sx += fabsf(q[r].x - prevw[r]);
      prevw[r] = q[r].w;
    }
#pragma unroll
    for (int r = 0; r < 3; ++r)    // dy within patch
      sy += fabsf(q[r + 1].x - q[r].x) + fabsf(q[r + 1].y - q[r].y)
          + fabsf(q[r + 1].z - q[r].z) + fabsf(q[r + 1].w - q[r].w);
    if (py < 63) {                 // dy boundary to next row band
      const float4 q4 = *(const float4*)(p0 + 4 * 256);
      sy += fabsf(q4.x - q[3].x) + fabsf(q4.y - q[3].y)
          + fabsf(q4.z - q[3].z) + fabsf(q4.w - q[3].w);
    }
    spraw += s; sgraw += s2;
    const float pm = fmaxf(s * 0.0625f, 0.f);
    const float gm = fmaxf(s2 * 0.0625f, 0.f);
    pdv[j] = pm; gdv[j] = gm; spd += pm; sgd += gm;
  }
  if ((t & 15) != 15) {            // dx boundary to next thread's cols
#pragma unroll
    for (int r = 0; r < 4; ++r)
      sx += fabsf(pb[rowbase + r * 256 + C0 + 16] - prevw[r]);
  }

  // block-reduce 6 values over 16 waves
  float r0 = spraw, r1 = sgraw, r2 = spd, r3 = sgd, r4 = sx, r5 = sy;
#pragma unroll
  for (int o = 32; o > 0; o >>= 1) {
    r0 += __shfl_down(r0, o); r1 += __shfl_down(r1, o);
    r2 += __shfl_down(r2, o); r3 += __shfl_down(r3, o);
    r4 += __shfl_down(r4, o); r5 += __shfl_down(r5, o);
  }
  if ((t & 63) == 0) {
    const int w = t >> 6;
    rbuf[w * 6 + 0] = r0; rbuf[w * 6 + 1] = r1; rbuf[w * 6 + 2] = r2;
    rbuf[w * 6 + 3] = r3; rbuf[w * 6 + 4] = r4; rbuf[w * 6 + 5] = r5;
  }
  __syncthreads();
  if (t == 0) {
    float a0 = 0, a1 = 0, a2 = 0, a3 = 0, a4 = 0, a5 = 0;
    for (int w = 0; w < 16; ++w) {
      a0 += rbuf[w * 6 + 0]; a1 += rbuf[w * 6 + 1]; a2 += rbuf[w * 6 + 2];
      a3 += rbuf[w * 6 + 3]; a4 += rbuf[w * 6 + 4]; a5 += rbuf[w * 6 + 5];
    }
    ws[b] = a0; ws[16 + b] = a1; ws[48 + b] = a4; ws[64 + b] = a5;
    rbuf[0] = a2; rbuf[1] = a3;
  }
  __syncthreads();
  const float Sp = rbuf[0], Sg = rbuf[1];

  // normalized a,b into LDS; v interior init = 1
#pragma unroll
  for (int j = 0; j < 4; ++j) {
    sa[py * 64 + px0 + j] = (Sp > 0.f) ? (pdv[j] / Sp) : (1.f / 4096.f);
    sb[py * 64 + px0 + j] = (Sg > 0.f) ? (gdv[j] / Sg) : (1.f / 4096.f);
  }
  const int ub = (py + 2) * PITCH + px0 + 2;
  sv[ub] = 1.f; sv[ub + 1] = 1.f; sv[ub + 2] = 1.f; sv[ub + 3] = 1.f;
  __syncthreads();

  // ---- Sinkhorn: 256 active threads, 4x4 tiles ----
  const bool act = (t < 256);
  const int ty = t >> 4, tx = t & 15;
  const int y0 = ty * 4, x0 = tx * 4;
  const int rdb = (y0 + 1) * PITCH + x0;      // window read base
  const int wbs = (y0 + 2) * PITCH + x0 + 2;  // interior write base

  float av[4][4], bv[4][4], uu[4][4], vv[4][4];
  if (act) {
#pragma unroll
    for (int i = 0; i < 4; ++i) {
      const float4 qa = *(const float4*)&sa[(y0 + i) * 64 + x0];
      av[i][0] = qa.x; av[i][1] = qa.y; av[i][2] = qa.z; av[i][3] = qa.w;
      const float4 qb = *(const float4*)&sb[(y0 + i) * 64 + x0];
      bv[i][0] = qb.x; bv[i][1] = qb.y; bv[i][2] = qb.z; bv[i][3] = qb.w;
    }
  }

#pragma unroll 1
  for (int it = 0; it < 50; ++it) {
    if (act) half_iter(sv, su, av, rdb, wbs, uu);  // u = a / (K v)
    __syncthreads();
    if (act) half_iter(su, sv, bv, rdb, wbs, vv);  // v = b / (K u)
    __syncthreads();
  }

  // cost_b = sum u_i * ((K.M) v)_i ; edges KW1, corners 2*exp(-40)
  float c = 0.f;
  if (act) {
    float w[6][8];
#pragma unroll
    for (int r = 0; r < 6; ++r) {
      const float4 A = *(const float4*)(sv + rdb + r * PITCH);
      const float4 B = *(const float4*)(sv + rdb + r * PITCH + 4);
      w[r][0] = A.x; w[r][1] = A.y; w[r][2] = A.z; w[r][3] = A.w;
      w[r][4] = B.x; w[r][5] = B.y; w[r][6] = B.z; w[r][7] = B.w;
    }
#pragma unroll
    for (int i = 0; i < 4; ++i)
#pragma unroll
      for (int j = 0; j < 4; ++j) {
        const float e = (w[i][j + 2] + w[i + 2][j + 2])
                      + (w[i + 1][j + 1] + w[i + 1][j + 3]);
        const float d = (w[i][j + 1] + w[i][j + 3])
                      + (w[i + 2][j + 1] + w[i + 2][j + 3]);
        c += uu[i][j] * fmaf(MW2, d, KW1 * e);
      }
  }
#pragma unroll
  for (int o = 32; o > 0; o >>= 1) c += __shfl_down(c, o);
  if ((t & 63) == 0) rbuf[t >> 6] = c;
  __syncthreads();
  if (t == 0) {
    float s = 0.f;
    for (int w = 0; w < 16; ++w) s += rbuf[w];
    ws[32 + b] = s;
  }
}

__global__ __launch_bounds__(64) void finalize_kernel(
    const float* __restrict__ ws, const int* __restrict__ epoch,
    const int* __restrict__ max_epoch, float* __restrict__ out) {
  const int t = threadIdx.x;
  float lc = 0.f, lot = 0.f, sx = 0.f, sy = 0.f;
  if (t < 16) {
    lc = fabsf(ws[t] - ws[16 + t]);
    lot = ws[32 + t];
    sx = ws[48 + t];
    sy = ws[64 + t];
  }
#pragma unroll
  for (int o = 8; o > 0; o >>= 1) {
    lc += __shfl_down(lc, o); lot += __shfl_down(lot, o);
    sx += __shfl_down(sx, o); sy += __shfl_down(sy, o);
  }
  if (t == 0) {
    int me = max_epoch[0]; if (me < 1) me = 1;
    const float tt = (float)epoch[0] / (float)me;
    const float ltv = sx / (16.f * 256.f * 255.f) + sy / (16.f * 255.f * 256.f);
    out[0] = lc * (1.f / 16.f) + tt * (lot * (1.f / 16.f)) + tt * ltv;
  }
}

extern "C" void kernel_launch(void* const* d_in, const int* in_sizes, int n_in,
                              void* d_out, int out_size, void* d_ws, size_t ws_size,
                              hipStream_t stream) {
  const float* pred = (const float*)d_in[0];
  const float* gt   = (const float*)d_in[1];
  const int* epoch  = (const int*)d_in[2];
  const int* max_ep = (const int*)d_in[3];
  float* out = (float*)d_out;
  float* ws  = (float*)d_ws;

  fused_kernel<<<dim3(16), dim3(1024), 0, stream>>>(pred, gt, ws);
  finalize_kernel<<<dim3(1), dim3(64), 0, stream>>>(ws, epoch, max_ep, out);
}

// Round 4
// 137.830 us; speedup vs baseline: 2.2609x; 1.2017x over previous
//
#include <hip/hip_runtime.h>
#include <math.h>

// ---------------------------------------------------------------------------
// CurriculumLoss: l_count + t*(OT via Sinkhorn on 64x64 downsample) + t*TV
//
// K = exp(-M/0.05) underflows to 0 in f32 for M >= 8; the surviving 9-tap
// kernel is exactly separable: (1, e^-20) (x) (1, e^-20). Sinkhorn becomes
// 100 half-steps of a separable 3x3 stencil + rcp on a 64x64 field.
//
// R4 structure (fixes R3's blow-up):
//  - 256 threads/block, one block per image; thread (tyg,tx) owns a 4x4
//    register tile; wave = 4 tile-rows x 16 tile-cols.
//  - Horizontal halo exchange via __shfl_up/down(..,1,16) on the freshly
//    computed registers -- NO unfenced LDS ordering anywhere (R3's bug:
//    compiler could hoist the intra-wave LDS column reads above the writes;
//    since the e^-20 taps are the sole stabilizer of the otherwise-divergent
//    pointwise iteration v <- (b/a) v, stale halos explode the iterate).
//  - Vertical halos: h-row LDS arrays double-buffered per phase (HTu/HBu vs
//    HTv/HBv), strictly barrier-separated. 2 barriers/iteration.
//  - Each thread pools its own 16x16 source patch straight into registers
//    (av/bv), fusing counts + TV in the same pass. 256 threads => no VGPR
//    spills (R2/R3 ran 1024 threads, <=128 VGPRs, and spilled ~2.2 MB).
//  - Finalize fused via ticket (memsetAsync counter + fence + atomicAdd).
// ---------------------------------------------------------------------------

#define KW1 2.0611536224385578e-09f  // exp(-20)
#define MW2 8.4967085105831778e-18f  // 2*exp(-40)
#define SP 68                        // h-slot stride (17 quads -> bank spread)
#define RP 72                        // raw-row stride, data at +2

__device__ __forceinline__ float ad4(const float4 a, const float4 b) {
  return fabsf(a.x - b.x) + fabsf(a.y - b.y) + fabsf(a.z - b.z) + fabsf(a.w - b.w);
}

// horizontal 3-tap with shfl halo exchange (segment of 16 lanes = tile row)
__device__ __forceinline__ void hpass_shfl(const float f[4][4], int tx,
                                           float h[4][4]) {
#pragma unroll
  for (int i = 0; i < 4; ++i) {
    float l = __shfl_up(f[i][3], 1, 16);    // left nbr's right col
    float r = __shfl_down(f[i][0], 1, 16);  // right nbr's left col
    l = (tx == 0) ? 0.f : l;                // field boundary = zero pad
    r = (tx == 15) ? 0.f : r;
    h[i][0] = fmaf(KW1, l + f[i][1], f[i][0]);
    h[i][1] = fmaf(KW1, f[i][0] + f[i][2], f[i][1]);
    h[i][2] = fmaf(KW1, f[i][1] + f[i][3], f[i][2]);
    h[i][3] = fmaf(KW1, f[i][2] + r, f[i][3]);
  }
}

// vertical 3-tap finish + rcp; hm/hp are cross-wave h halos (barrier-safe)
__device__ __forceinline__ void vert(const float h[4][4], const float4 hm,
                                     const float4 hp, const float cf[4][4],
                                     float o[4][4]) {
  const float m[4] = {hm.x, hm.y, hm.z, hm.w};
  const float p[4] = {hp.x, hp.y, hp.z, hp.w};
#pragma unroll
  for (int j = 0; j < 4; ++j) {
    o[0][j] = cf[0][j] * __builtin_amdgcn_rcpf(fmaf(KW1, m[j] + h[1][j], h[0][j]));
    o[1][j] = cf[1][j] * __builtin_amdgcn_rcpf(fmaf(KW1, h[0][j] + h[2][j], h[1][j]));
    o[2][j] = cf[2][j] * __builtin_amdgcn_rcpf(fmaf(KW1, h[1][j] + h[3][j], h[2][j]));
    o[3][j] = cf[3][j] * __builtin_amdgcn_rcpf(fmaf(KW1, h[2][j] + p[j], h[3][j]));
  }
}

// ws layout (floats): pc[0..16) gc[16..32) cost[32..48) tvx[48..64) tvy[64..80)
// counter: dword at byte offset 384 (float idx 96), memset to 0 pre-launch.
__global__ __launch_bounds__(256) void fused_kernel(
    const float* __restrict__ pred, const float* __restrict__ gt,
    float* __restrict__ ws, const int* __restrict__ epoch,
    const int* __restrict__ max_epoch, float* __restrict__ out,
    unsigned int* __restrict__ cnt) {
  __shared__ float HTu[18 * SP], HBu[18 * SP], HTv[18 * SP], HBv[18 * SP];
  __shared__ float RTs[18 * RP], RBs[18 * RP];
  __shared__ float rbuf[24];

  const int b = blockIdx.x;
  const int t = threadIdx.x;
  const int tyg = t >> 4, tx = t & 15;      // tile coords
  const int y0 = tyg * 4, x0 = tx * 4;

  // zero exchange arrays (boundary slots 0/17 must stay zero forever)
  for (int i = t; i < 18 * SP; i += 256) {
    HTu[i] = 0.f; HBu[i] = 0.f; HTv[i] = 0.f; HBv[i] = 0.f;
  }
  for (int i = t; i < 18 * RP; i += 256) { RTs[i] = 0.f; RBs[i] = 0.f; }

  // ---- prologue: pool own 16x16 source patch + counts + TV ----
  const float* pb = pred + b * 65536;
  const float* gb = gt + b * 65536;
  const int sr0 = 4 * y0, sc0 = 4 * x0;

  float pd[4][4] = {{0.f}}, gd[4][4] = {{0.f}};
  float4 pr0, pr1, pr2, pr3;
  float spraw = 0.f, sgraw = 0.f, sx = 0.f, sy = 0.f;
#pragma unroll
  for (int i = 0; i < 4; ++i) {
#pragma unroll
    for (int rr = 0; rr < 4; ++rr) {
      const int r = i * 4 + rr;
      const float* prow = pb + (sr0 + r) * 256 + sc0;
      const float4 q0 = *(const float4*)(prow);
      const float4 q1 = *(const float4*)(prow + 4);
      const float4 q2 = *(const float4*)(prow + 8);
      const float4 q3 = *(const float4*)(prow + 12);
      const float s0 = (q0.x + q0.y) + (q0.z + q0.w);
      const float s1 = (q1.x + q1.y) + (q1.z + q1.w);
      const float s2 = (q2.x + q2.y) + (q2.z + q2.w);
      const float s3 = (q3.x + q3.y) + (q3.z + q3.w);
      pd[i][0] += s0; pd[i][1] += s1; pd[i][2] += s2; pd[i][3] += s3;
      spraw += (s0 + s1) + (s2 + s3);
      // TV dx: 15 internal pairs + boundary to right thread's first col
      sx += fabsf(q0.y - q0.x) + fabsf(q0.z - q0.y) + fabsf(q0.w - q0.z)
          + fabsf(q1.x - q0.w)
          + fabsf(q1.y - q1.x) + fabsf(q1.z - q1.y) + fabsf(q1.w - q1.z)
          + fabsf(q2.x - q1.w)
          + fabsf(q2.y - q2.x) + fabsf(q2.z - q2.y) + fabsf(q2.w - q2.z)
          + fabsf(q3.x - q2.w)
          + fabsf(q3.y - q3.x) + fabsf(q3.z - q3.y) + fabsf(q3.w - q3.z);
      const float nf = __shfl_down(q0.x, 1, 16);  // right nbr col 4*x0+16
      if (tx < 15) sx += fabsf(nf - q3.w);
      // TV dy vs previous row
      if (r > 0) sy += ad4(q0, pr0) + ad4(q1, pr1) + ad4(q2, pr2) + ad4(q3, pr3);
      pr0 = q0; pr1 = q1; pr2 = q2; pr3 = q3;
      // gt: pooling + count only
      const float* grow = gb + (sr0 + r) * 256 + sc0;
      const float4 g0 = *(const float4*)(grow);
      const float4 g1 = *(const float4*)(grow + 4);
      const float4 g2 = *(const float4*)(grow + 8);
      const float4 g3 = *(const float4*)(grow + 12);
      const float u0 = (g0.x + g0.y) + (g0.z + g0.w);
      const float u1 = (g1.x + g1.y) + (g1.z + g1.w);
      const float u2 = (g2.x + g2.y) + (g2.z + g2.w);
      const float u3 = (g3.x + g3.y) + (g3.z + g3.w);
      gd[i][0] += u0; gd[i][1] += u1; gd[i][2] += u2; gd[i][3] += u3;
      sgraw += (u0 + u1) + (u2 + u3);
    }
  }
  if (tyg < 15) {  // dy boundary pair (row sr0+15, sr0+16)
    const float* prow = pb + (sr0 + 16) * 256 + sc0;
    sy += ad4(*(const float4*)(prow), pr0) + ad4(*(const float4*)(prow + 4), pr1)
        + ad4(*(const float4*)(prow + 8), pr2) + ad4(*(const float4*)(prow + 12), pr3);
  }

  // relu(avg-pool) and pooled sums
  float spd = 0.f, sgd = 0.f;
#pragma unroll
  for (int i = 0; i < 4; ++i)
#pragma unroll
    for (int j = 0; j < 4; ++j) {
      pd[i][j] = fmaxf(pd[i][j] * 0.0625f, 0.f); spd += pd[i][j];
      gd[i][j] = fmaxf(gd[i][j] * 0.0625f, 0.f); sgd += gd[i][j];
    }

  // block-reduce 6 values over 4 waves
  float r0 = spraw, r1 = sgraw, r2 = spd, r3 = sgd, r4 = sx, r5 = sy;
#pragma unroll
  for (int o = 32; o > 0; o >>= 1) {
    r0 += __shfl_down(r0, o); r1 += __shfl_down(r1, o);
    r2 += __shfl_down(r2, o); r3 += __shfl_down(r3, o);
    r4 += __shfl_down(r4, o); r5 += __shfl_down(r5, o);
  }
  if ((t & 63) == 0) {
    const int w = t >> 6;
    rbuf[w * 6 + 0] = r0; rbuf[w * 6 + 1] = r1; rbuf[w * 6 + 2] = r2;
    rbuf[w * 6 + 3] = r3; rbuf[w * 6 + 4] = r4; rbuf[w * 6 + 5] = r5;
  }
  __syncthreads();
  if (t == 0) {
    float a0 = 0, a1 = 0, a2 = 0, a3 = 0, a4 = 0, a5 = 0;
    for (int w = 0; w < 4; ++w) {
      a0 += rbuf[w * 6 + 0]; a1 += rbuf[w * 6 + 1]; a2 += rbuf[w * 6 + 2];
      a3 += rbuf[w * 6 + 3]; a4 += rbuf[w * 6 + 4]; a5 += rbuf[w * 6 + 5];
    }
    ws[b] = a0; ws[16 + b] = a1; ws[48 + b] = a4; ws[64 + b] = a5;
    rbuf[0] = a2; rbuf[1] = a3;
  }
  __syncthreads();
  const float Sp = rbuf[0], Sg = rbuf[1];

  float av[4][4], bv[4][4];
#pragma unroll
  for (int i = 0; i < 4; ++i)
#pragma unroll
    for (int j = 0; j < 4; ++j) {
      av[i][j] = (Sp > 0.f) ? (pd[i][j] / Sp) : (1.f / 4096.f);
      bv[i][j] = (Sg > 0.f) ? (gd[i][j] / Sg) : (1.f / 4096.f);
    }

  // ---- Sinkhorn: 4x4 register tiles, shfl columns, LDS h-rows ----
  const int htw = (1 + tyg) * SP + x0;   // own h slot
  const int hbr = tyg * SP + x0;         // above nbr's bottom h (slot0=zeros)
  const int htr = (2 + tyg) * SP + x0;   // below nbr's top h (slot17=zeros)

  float uu[4][4], vv[4][4], h[4][4];
#pragma unroll
  for (int i = 0; i < 4; ++i)
#pragma unroll
    for (int j = 0; j < 4; ++j) vv[i][j] = 1.f;
  hpass_shfl(vv, tx, h);                 // h_v for v = ones
  *(float4*)&HTv[htw] = make_float4(h[0][0], h[0][1], h[0][2], h[0][3]);
  *(float4*)&HBv[htw] = make_float4(h[3][0], h[3][1], h[3][2], h[3][3]);
  __syncthreads();

#pragma unroll 1
  for (int it = 0; it < 50; ++it) {
    // u = a / (K v)
    {
      const float4 hm = *(const float4*)&HBv[hbr];
      const float4 hp = *(const float4*)&HTv[htr];
      vert(h, hm, hp, av, uu);
      hpass_shfl(uu, tx, h);             // h_u from fresh registers
      *(float4*)&HTu[htw] = make_float4(h[0][0], h[0][1], h[0][2], h[0][3]);
      *(float4*)&HBu[htw] = make_float4(h[3][0], h[3][1], h[3][2], h[3][3]);
    }
    __syncthreads();
    // v = b / (K u)
    {
      const float4 hm = *(const float4*)&HBu[hbr];
      const float4 hp = *(const float4*)&HTu[htr];
      vert(h, hm, hp, bv, vv);
      hpass_shfl(vv, tx, h);             // h_v
      *(float4*)&HTv[htw] = make_float4(h[0][0], h[0][1], h[0][2], h[0][3]);
      *(float4*)&HBv[htw] = make_float4(h[3][0], h[3][1], h[3][2], h[3][3]);
    }
    __syncthreads();
  }

  // ---- cost epilogue: 6x6 ring of final v (K.M not separable) ----
  *(float2*)&RTs[(1 + tyg) * RP + 2 + x0]     = make_float2(vv[0][0], vv[0][1]);
  *(float2*)&RTs[(1 + tyg) * RP + 4 + x0]     = make_float2(vv[0][2], vv[0][3]);
  *(float2*)&RBs[(1 + tyg) * RP + 2 + x0]     = make_float2(vv[3][0], vv[3][1]);
  *(float2*)&RBs[(1 + tyg) * RP + 4 + x0]     = make_float2(vv[3][2], vv[3][3]);
  __syncthreads();
  float c = 0.f;
  {
    const float4 t0 = *(const float4*)&RBs[tyg * RP + x0];        // row y0-1
    const float4 t1 = *(const float4*)&RBs[tyg * RP + x0 + 4];
    const float4 b0 = *(const float4*)&RTs[(tyg + 2) * RP + x0];  // row y0+4
    const float4 b1 = *(const float4*)&RTs[(tyg + 2) * RP + x0 + 4];
    float W[6][6];
    W[0][0] = t0.y; W[0][1] = t0.z; W[0][2] = t0.w;
    W[0][3] = t1.x; W[0][4] = t1.y; W[0][5] = t1.z;
    W[5][0] = b0.y; W[5][1] = b0.z; W[5][2] = b0.w;
    W[5][3] = b1.x; W[5][4] = b1.y; W[5][5] = b1.z;
#pragma unroll
    for (int i = 0; i < 4; ++i) {
      float l = __shfl_up(vv[i][3], 1, 16);
      float r = __shfl_down(vv[i][0], 1, 16);
      W[1 + i][0] = (tx == 0) ? 0.f : l;
      W[1 + i][5] = (tx == 15) ? 0.f : r;
#pragma unroll
      for (int j = 0; j < 4; ++j) W[1 + i][1 + j] = vv[i][j];
    }
#pragma unroll
    for (int i = 0; i < 4; ++i)
#pragma unroll
      for (int j = 0; j < 4; ++j) {
        const float e = (W[i][j + 1] + W[i + 2][j + 1])
                      + (W[i + 1][j] + W[i + 1][j + 2]);
        const float d = (W[i][j] + W[i][j + 2])
                      + (W[i + 2][j] + W[i + 2][j + 2]);
        c += uu[i][j] * fmaf(MW2, d, KW1 * e);
      }
  }
#pragma unroll
  for (int o = 32; o > 0; o >>= 1) c += __shfl_down(c, o);
  if ((t & 63) == 0) rbuf[t >> 6] = c;
  __syncthreads();
  if (t == 0) {
    ws[32 + b] = rbuf[0] + rbuf[1] + rbuf[2] + rbuf[3];
    // ---- ticket: last block finalizes ----
    __threadfence();
    const unsigned int old = atomicAdd(cnt, 1u);
    if (old == 15u) {
      __threadfence();
      float lc = 0.f, lot = 0.f, tvx = 0.f, tvy = 0.f;
      for (int k = 0; k < 16; ++k) {
        const float p  = __hip_atomic_load(&ws[k],      __ATOMIC_RELAXED, __HIP_MEMORY_SCOPE_AGENT);
        const float g  = __hip_atomic_load(&ws[16 + k], __ATOMIC_RELAXED, __HIP_MEMORY_SCOPE_AGENT);
        const float ct = __hip_atomic_load(&ws[32 + k], __ATOMIC_RELAXED, __HIP_MEMORY_SCOPE_AGENT);
        const float x  = __hip_atomic_load(&ws[48 + k], __ATOMIC_RELAXED, __HIP_MEMORY_SCOPE_AGENT);
        const float y  = __hip_atomic_load(&ws[64 + k], __ATOMIC_RELAXED, __HIP_MEMORY_SCOPE_AGENT);
        lc += fabsf(p - g); lot += ct; tvx += x; tvy += y;
      }
      int me = max_epoch[0]; if (me < 1) me = 1;
      const float tt = (float)epoch[0] / (float)me;
      const float ltv = tvx / (16.f * 256.f * 255.f) + tvy / (16.f * 255.f * 256.f);
      out[0] = lc * (1.f / 16.f) + tt * (lot * (1.f / 16.f)) + tt * ltv;
    }
  }
}

extern "C" void kernel_launch(void* const* d_in, const int* in_sizes, int n_in,
                              void* d_out, int out_size, void* d_ws, size_t ws_size,
                              hipStream_t stream) {
  const float* pred = (const float*)d_in[0];
  const float* gt   = (const float*)d_in[1];
  const int* epoch  = (const int*)d_in[2];
  const int* max_ep = (const int*)d_in[3];
  float* out = (float*)d_out;
  float* ws  = (float*)d_ws;
  unsigned int* cnt = (unsigned int*)((char*)d_ws + 384);

  hipMemsetAsync(cnt, 0, 4, stream);
  fused_kernel<<<dim3(16), dim3(256), 0, stream>>>(pred, gt, ws, epoch,
                                                   max_ep, out, cnt);
}

// Round 5
// 123.542 us; speedup vs baseline: 2.5223x; 1.1157x over previous
//
#include <hip/hip_runtime.h>
#include <math.h>

// ---------------------------------------------------------------------------
// CurriculumLoss: l_count + t*(OT via Sinkhorn on 64x64 downsample) + t*TV
//
// K = exp(-M/0.05) underflows to 0 in f32 for M >= 8; the surviving 9-tap
// kernel is exactly separable: (1, e^-20) (x) (1, e^-20). Sinkhorn becomes
// 100 half-steps of a separable 3x3 stencil + rcp on a 64x64 field.
//
// R5 (fixes R4's VGPR=256 + 4 MB scratch spill, pipelines the half-step):
//  - 256 threads/block, one block/image; thread (tyg,tx) owns a 4x4 register
//    tile; wave = 4 tile-rows x 16 tile-cols.
//  - Horizontal halos via __shfl_up/down(..,1,16) on fresh registers.
//  - Vertical halos: per-phase double-buffered LDS h-rows (HTu/HBu, HTv/HBv),
//    strictly barrier-separated; 2 barriers/iteration.
//  - PIPELINED half-step: after the barrier, issue hm/hp ds_reads, compute the
//    PREVIOUS field's interior h-rows (shfl-only) under the read latency, then
//    vert + edge-h + LDS write + barrier. Interior work stays off the
//    inter-wave critical path.
//  - Prologue pools each thread's own 16x16 patch with an outer-unrolled(4) x
//    inner runtime(unroll 1) loop so the scheduler cannot cluster 64 float4
//    loads (R4: that clustering hit the 256-VGPR cap and spilled ~4 MB).
//  - Finalize fused via ticket (memsetAsync counter + fence + atomicAdd).
// ---------------------------------------------------------------------------

#define KW1 2.0611536224385578e-09f  // exp(-20)
#define MW2 8.4967085105831778e-18f  // 2*exp(-40)
#define SP 68                        // h-slot stride (17 quads -> bank spread)
#define RP 72                        // raw-row stride, data at +2

__device__ __forceinline__ float ad4(const float4 a, const float4 b) {
  return fabsf(a.x - b.x) + fabsf(a.y - b.y) + fabsf(a.z - b.z) + fabsf(a.w - b.w);
}

// horizontal 3-tap for one row with shfl halo exchange (16-lane segments)
__device__ __forceinline__ void hrow(const float f[4], int tx, float h[4]) {
  float l = __shfl_up(f[3], 1, 16);    // left nbr's right col
  float r = __shfl_down(f[0], 1, 16);  // right nbr's left col
  l = (tx == 0) ? 0.f : l;             // field boundary = zero pad
  r = (tx == 15) ? 0.f : r;
  h[0] = fmaf(KW1, l + f[1], f[0]);
  h[1] = fmaf(KW1, f[0] + f[2], f[1]);
  h[2] = fmaf(KW1, f[1] + f[3], f[2]);
  h[3] = fmaf(KW1, f[2] + r, f[3]);
}

// One pipelined half-step. prev = previous phase's field (rows 1,2 feed the
// deferred interior h); h0/h3 = previous field's edge h (computed last phase).
// Reads hm/hp halos, verts all 4 rows, computes+writes the OUTPUT field's
// edge h. Caller barriers after.
__device__ __forceinline__ void half_step(
    const float prev[4][4], const float h0[4], const float h3[4],
    const float cf[4][4],
    const float* __restrict__ HB_rd, const float* __restrict__ HT_rd,
    float* __restrict__ HT_wr, float* __restrict__ HB_wr,
    int hbr, int htr, int htw, int tx,
    float out[4][4], float oh0[4], float oh3[4]) {
  const float4 hm4 = *(const float4*)&HB_rd[hbr];   // issue early
  const float4 hp4 = *(const float4*)&HT_rd[htr];
  float h1[4], h2[4];
  hrow(prev[1], tx, h1);                // deferred interior h: overlaps reads
  hrow(prev[2], tx, h2);
  const float m[4] = {hm4.x, hm4.y, hm4.z, hm4.w};
  const float p[4] = {hp4.x, hp4.y, hp4.z, hp4.w};
#pragma unroll
  for (int j = 0; j < 4; ++j) {
    out[0][j] = cf[0][j] * __builtin_amdgcn_rcpf(fmaf(KW1, m[j] + h1[j], h0[j]));
    out[1][j] = cf[1][j] * __builtin_amdgcn_rcpf(fmaf(KW1, h0[j] + h2[j], h1[j]));
    out[2][j] = cf[2][j] * __builtin_amdgcn_rcpf(fmaf(KW1, h1[j] + h3[j], h2[j]));
    out[3][j] = cf[3][j] * __builtin_amdgcn_rcpf(fmaf(KW1, h2[j] + p[j], h3[j]));
  }
  hrow(out[0], tx, oh0);                // only edge h before the barrier
  hrow(out[3], tx, oh3);
  *(float4*)&HT_wr[htw] = make_float4(oh0[0], oh0[1], oh0[2], oh0[3]);
  *(float4*)&HB_wr[htw] = make_float4(oh3[0], oh3[1], oh3[2], oh3[3]);
}

// ws layout (floats): pc[0..16) gc[16..32) cost[32..48) tvx[48..64) tvy[64..80)
// counter: dword at byte offset 384 (float idx 96), memset to 0 pre-launch.
__global__ __launch_bounds__(256) void fused_kernel(
    const float* __restrict__ pred, const float* __restrict__ gt,
    float* __restrict__ ws, const int* __restrict__ epoch,
    const int* __restrict__ max_epoch, float* __restrict__ out,
    unsigned int* __restrict__ cnt) {
  __shared__ float HTu[18 * SP], HBu[18 * SP], HTv[18 * SP], HBv[18 * SP];
  __shared__ float RTs[18 * RP], RBs[18 * RP];
  __shared__ float rbuf[24];

  const int b = blockIdx.x;
  const int t = threadIdx.x;
  const int tyg = t >> 4, tx = t & 15;      // tile coords
  const int y0 = tyg * 4, x0 = tx * 4;

  // zero exchange arrays (boundary slots 0/17 must stay zero forever)
  for (int i = t; i < 18 * SP; i += 256) {
    HTu[i] = 0.f; HBu[i] = 0.f; HTv[i] = 0.f; HBv[i] = 0.f;
  }
  for (int i = t; i < 18 * RP; i += 256) { RTs[i] = 0.f; RBs[i] = 0.f; }

  // ---- prologue: pool own 16x16 source patch + counts + TV ----
  // Outer unrolled(4) x inner runtime(unroll 1): keeps the global-load window
  // at 8 float4s so the scheduler can't cluster 64 loads and spill (R4 bug).
  const float* pb = pred + b * 65536;
  const float* gb = gt + b * 65536;
  const int sr0 = 4 * y0, sc0 = 4 * x0;

  float pd[4][4], gd[4][4];
  float4 pr0, pr1, pr2, pr3;
  float spraw = 0.f, sgraw = 0.f, sx = 0.f, sy = 0.f;
#pragma unroll
  for (int i = 0; i < 4; ++i) {
    float a0 = 0.f, a1 = 0.f, a2 = 0.f, a3 = 0.f;
    float c0 = 0.f, c1 = 0.f, c2 = 0.f, c3 = 0.f;
#pragma unroll 1
    for (int rr = 0; rr < 4; ++rr) {
      const int r = i * 4 + rr;
      const float* prow = pb + (sr0 + r) * 256 + sc0;
      const float4 q0 = *(const float4*)(prow);
      const float4 q1 = *(const float4*)(prow + 4);
      const float4 q2 = *(const float4*)(prow + 8);
      const float4 q3 = *(const float4*)(prow + 12);
      const float s0 = (q0.x + q0.y) + (q0.z + q0.w);
      const float s1 = (q1.x + q1.y) + (q1.z + q1.w);
      const float s2 = (q2.x + q2.y) + (q2.z + q2.w);
      const float s3 = (q3.x + q3.y) + (q3.z + q3.w);
      a0 += s0; a1 += s1; a2 += s2; a3 += s3;
      spraw += (s0 + s1) + (s2 + s3);
      // TV dx: 15 internal pairs + boundary to right thread's first col
      sx += fabsf(q0.y - q0.x) + fabsf(q0.z - q0.y) + fabsf(q0.w - q0.z)
          + fabsf(q1.x - q0.w)
          + fabsf(q1.y - q1.x) + fabsf(q1.z - q1.y) + fabsf(q1.w - q1.z)
          + fabsf(q2.x - q1.w)
          + fabsf(q2.y - q2.x) + fabsf(q2.z - q2.y) + fabsf(q2.w - q2.z)
          + fabsf(q3.x - q2.w)
          + fabsf(q3.y - q3.x) + fabsf(q3.z - q3.y) + fabsf(q3.w - q3.z);
      const float nf = __shfl_down(q0.x, 1, 16);  // right nbr col sc0+16
      if (tx < 15) sx += fabsf(nf - q3.w);
      // TV dy vs previous row
      if (r > 0) sy += ad4(q0, pr0) + ad4(q1, pr1) + ad4(q2, pr2) + ad4(q3, pr3);
      pr0 = q0; pr1 = q1; pr2 = q2; pr3 = q3;
      // gt: pooling + count only
      const float* grow = gb + (sr0 + r) * 256 + sc0;
      const float4 g0 = *(const float4*)(grow);
      const float4 g1 = *(const float4*)(grow + 4);
      const float4 g2 = *(const float4*)(grow + 8);
      const float4 g3 = *(const float4*)(grow + 12);
      const float u0 = (g0.x + g0.y) + (g0.z + g0.w);
      const float u1 = (g1.x + g1.y) + (g1.z + g1.w);
      const float u2 = (g2.x + g2.y) + (g2.z + g2.w);
      const float u3 = (g3.x + g3.y) + (g3.z + g3.w);
      c0 += u0; c1 += u1; c2 += u2; c3 += u3;
      sgraw += (u0 + u1) + (u2 + u3);
    }
    pd[i][0] = a0; pd[i][1] = a1; pd[i][2] = a2; pd[i][3] = a3;
    gd[i][0] = c0; gd[i][1] = c1; gd[i][2] = c2; gd[i][3] = c3;
  }
  if (tyg < 15) {  // dy boundary pair (row sr0+15, sr0+16)
    const float* prow = pb + (sr0 + 16) * 256 + sc0;
    sy += ad4(*(const float4*)(prow), pr0) + ad4(*(const float4*)(prow + 4), pr1)
        + ad4(*(const float4*)(prow + 8), pr2) + ad4(*(const float4*)(prow + 12), pr3);
  }

  // relu(avg-pool) and pooled sums
  float spd = 0.f, sgd = 0.f;
#pragma unroll
  for (int i = 0; i < 4; ++i)
#pragma unroll
    for (int j = 0; j < 4; ++j) {
      pd[i][j] = fmaxf(pd[i][j] * 0.0625f, 0.f); spd += pd[i][j];
      gd[i][j] = fmaxf(gd[i][j] * 0.0625f, 0.f); sgd += gd[i][j];
    }

  // block-reduce 6 values over 4 waves
  float r0 = spraw, r1 = sgraw, r2 = spd, r3 = sgd, r4 = sx, r5 = sy;
#pragma unroll
  for (int o = 32; o > 0; o >>= 1) {
    r0 += __shfl_down(r0, o); r1 += __shfl_down(r1, o);
    r2 += __shfl_down(r2, o); r3 += __shfl_down(r3, o);
    r4 += __shfl_down(r4, o); r5 += __shfl_down(r5, o);
  }
  if ((t & 63) == 0) {
    const int w = t >> 6;
    rbuf[w * 6 + 0] = r0; rbuf[w * 6 + 1] = r1; rbuf[w * 6 + 2] = r2;
    rbuf[w * 6 + 3] = r3; rbuf[w * 6 + 4] = r4; rbuf[w * 6 + 5] = r5;
  }
  __syncthreads();
  if (t == 0) {
    float a0 = 0, a1 = 0, a2 = 0, a3 = 0, a4 = 0, a5 = 0;
    for (int w = 0; w < 4; ++w) {
      a0 += rbuf[w * 6 + 0]; a1 += rbuf[w * 6 + 1]; a2 += rbuf[w * 6 + 2];
      a3 += rbuf[w * 6 + 3]; a4 += rbuf[w * 6 + 4]; a5 += rbuf[w * 6 + 5];
    }
    ws[b] = a0; ws[16 + b] = a1; ws[48 + b] = a4; ws[64 + b] = a5;
    rbuf[0] = a2; rbuf[1] = a3;
  }
  __syncthreads();
  const float Sp = rbuf[0], Sg = rbuf[1];

  float av[4][4], bv[4][4];
#pragma unroll
  for (int i = 0; i < 4; ++i)
#pragma unroll
    for (int j = 0; j < 4; ++j) {
      av[i][j] = (Sp > 0.f) ? (pd[i][j] / Sp) : (1.f / 4096.f);
      bv[i][j] = (Sg > 0.f) ? (gd[i][j] / Sg) : (1.f / 4096.f);
    }

  // ---- Sinkhorn: 4x4 register tiles, shfl columns, pipelined LDS h-rows ----
  const int htw = (1 + tyg) * SP + x0;   // own h slot
  const int hbr = tyg * SP + x0;         // above nbr's bottom h (slot0=zeros)
  const int htr = (2 + tyg) * SP + x0;   // below nbr's top h (slot17=zeros)

  float uu[4][4], vv[4][4], hu0[4], hu3[4], hv0[4], hv3[4];
#pragma unroll
  for (int i = 0; i < 4; ++i)
#pragma unroll
    for (int j = 0; j < 4; ++j) vv[i][j] = 1.f;
  hrow(vv[0], tx, hv0);                  // edge h for v = ones
  hrow(vv[3], tx, hv3);
  *(float4*)&HTv[htw] = make_float4(hv0[0], hv0[1], hv0[2], hv0[3]);
  *(float4*)&HBv[htw] = make_float4(hv3[0], hv3[1], hv3[2], hv3[3]);
  __syncthreads();

#pragma unroll 1
  for (int it = 0; it < 50; ++it) {
    // u = a / (K v)
    half_step(vv, hv0, hv3, av, HBv, HTv, HTu, HBu, hbr, htr, htw, tx,
              uu, hu0, hu3);
    __syncthreads();
    // v = b / (K u)
    half_step(uu, hu0, hu3, bv, HBu, HTu, HTv, HBv, hbr, htr, htw, tx,
              vv, hv0, hv3);
    __syncthreads();
  }

  // ---- cost epilogue: 6x6 ring of final v (K.M not separable) ----
  *(float2*)&RTs[(1 + tyg) * RP + 2 + x0] = make_float2(vv[0][0], vv[0][1]);
  *(float2*)&RTs[(1 + tyg) * RP + 4 + x0] = make_float2(vv[0][2], vv[0][3]);
  *(float2*)&RBs[(1 + tyg) * RP + 2 + x0] = make_float2(vv[3][0], vv[3][1]);
  *(float2*)&RBs[(1 + tyg) * RP + 4 + x0] = make_float2(vv[3][2], vv[3][3]);
  __syncthreads();
  float c = 0.f;
  {
    const float4 t0 = *(const float4*)&RBs[tyg * RP + x0];        // row y0-1
    const float4 t1 = *(const float4*)&RBs[tyg * RP + x0 + 4];
    const float4 b0 = *(const float4*)&RTs[(tyg + 2) * RP + x0];  // row y0+4
    const float4 b1 = *(const float4*)&RTs[(tyg + 2) * RP + x0 + 4];
    float W[6][6];
    W[0][0] = t0.y; W[0][1] = t0.z; W[0][2] = t0.w;
    W[0][3] = t1.x; W[0][4] = t1.y; W[0][5] = t1.z;
    W[5][0] = b0.y; W[5][1] = b0.z; W[5][2] = b0.w;
    W[5][3] = b1.x; W[5][4] = b1.y; W[5][5] = b1.z;
#pragma unroll
    for (int i = 0; i < 4; ++i) {
      float l = __shfl_up(vv[i][3], 1, 16);
      float r = __shfl_down(vv[i][0], 1, 16);
      W[1 + i][0] = (tx == 0) ? 0.f : l;
      W[1 + i][5] = (tx == 15) ? 0.f : r;
#pragma unroll
      for (int j = 0; j < 4; ++j) W[1 + i][1 + j] = vv[i][j];
    }
#pragma unroll
    for (int i = 0; i < 4; ++i)
#pragma unroll
      for (int j = 0; j < 4; ++j) {
        const float e = (W[i][j + 1] + W[i + 2][j + 1])
                      + (W[i + 1][j] + W[i + 1][j + 2]);
        const float d = (W[i][j] + W[i][j + 2])
                      + (W[i + 2][j] + W[i + 2][j + 2]);
        c += uu[i][j] * fmaf(MW2, d, KW1 * e);
      }
  }
#pragma unroll
  for (int o = 32; o > 0; o >>= 1) c += __shfl_down(c, o);
  if ((t & 63) == 0) rbuf[t >> 6] = c;
  __syncthreads();
  if (t == 0) {
    ws[32 + b] = rbuf[0] + rbuf[1] + rbuf[2] + rbuf[3];
    // ---- ticket: last block finalizes ----
    __threadfence();
    const unsigned int old = atomicAdd(cnt, 1u);
    if (old == 15u) {
      __threadfence();
      float lc = 0.f, lot = 0.f, tvx = 0.f, tvy = 0.f;
      for (int k = 0; k < 16; ++k) {
        const float p  = __hip_atomic_load(&ws[k],      __ATOMIC_RELAXED, __HIP_MEMORY_SCOPE_AGENT);
        const float g  = __hip_atomic_load(&ws[16 + k], __ATOMIC_RELAXED, __HIP_MEMORY_SCOPE_AGENT);
        const float ct = __hip_atomic_load(&ws[32 + k], __ATOMIC_RELAXED, __HIP_MEMORY_SCOPE_AGENT);
        const float x  = __hip_atomic_load(&ws[48 + k], __ATOMIC_RELAXED, __HIP_MEMORY_SCOPE_AGENT);
        const float y  = __hip_atomic_load(&ws[64 + k], __ATOMIC_RELAXED, __HIP_MEMORY_SCOPE_AGENT);
        lc += fabsf(p - g); lot += ct; tvx += x; tvy += y;
      }
      int me = max_epoch[0]; if (me < 1) me = 1;
      const float tt = (float)epoch[0] / (float)me;
      const float ltv = tvx / (16.f * 256.f * 255.f) + tvy / (16.f * 255.f * 256.f);
      out[0] = lc * (1.f / 16.f) + tt * (lot * (1.f / 16.f)) + tt * ltv;
    }
  }
}

extern "C" void kernel_launch(void* const* d_in, const int* in_sizes, int n_in,
                              void* d_out, int out_size, void* d_ws, size_t ws_size,
                              hipStream_t stream) {
  const float* pred = (const float*)d_in[0];
  const float* gt   = (const float*)d_in[1];
  const int* epoch  = (const int*)d_in[2];
  const int* max_ep = (const int*)d_in[3];
  float* out = (float*)d_out;
  float* ws  = (float*)d_ws;
  unsigned int* cnt = (unsigned int*)((char*)d_ws + 384);

  hipMemsetAsync(cnt, 0, 4, stream);
  fused_kernel<<<dim3(16), dim3(256), 0, stream>>>(pred, gt, ws, epoch,
                                                   max_ep, out, cnt);
}

// Round 6
// 120.828 us; speedup vs baseline: 2.5790x; 1.0225x over previous
//
#include <hip/hip_runtime.h>
#include <math.h>

// ---------------------------------------------------------------------------
// CurriculumLoss: l_count + t*(OT via Sinkhorn on 64x64 downsample) + t*TV
//
// K = exp(-M/0.05) underflows to 0 in f32 for M >= 8; the surviving 9-tap
// kernel is exactly separable: (1, e^-20) (x) (1, e^-20). Sinkhorn becomes
// 100 half-steps of a separable 3x3 stencil + rcp on a 64x64 field.
//
// R6 (cuts R5's latency chain; arithmetic identical):
//  - Horizontal halos via DPP row_shr:1 / row_shl:1 (16-lane DPP rows ==
//    our tile-row segments; bound_ctrl zero-fill == field boundary). VALU,
//    no DS pipe, no 120-cyc bpermute on the critical path.
//  - Vertical halos: publish RAW edge rows (2x ds_write_b128) into per-phase
//    double-buffered arrays; the consumer computes the neighbor's h itself
//    from a 6-wide raw window (b64+b128+b64 reads + 8 fma). Producer's
//    post-vert path = just the two writes.
//  - Interior rows 1,2 of each new field need no cross-thread halos -> их
//    computation is DEFERRED past the barrier, overlapping the halo ds_read
//    latency of the next half-step.
//  - 256 threads/block, one block/image, thread (tyg,tx) owns a 4x4 tile.
//  - Prologue (pool+counts+TV) and ticket-fused finalize as in R5.
// ---------------------------------------------------------------------------

#define KW1 2.0611536224385578e-09f  // exp(-20)
#define MW2 8.4967085105831778e-18f  // 2*exp(-40)
#define RP2 72                       // row storage: cols -4..67 at +4, 16B-aligned writes

// DPP lane shifts within 16-lane rows (= tile-row segments).
__device__ __forceinline__ float dpp_left(float x) {   // lane tx-1's value; 0 at tx==0
  return __int_as_float(__builtin_amdgcn_update_dpp(
      0, __float_as_int(x), 0x111, 0xF, 0xF, true));   // row_shr:1, zero-bound
}
__device__ __forceinline__ float dpp_right(float x) {  // lane tx+1's value; 0 at tx==15
  return __int_as_float(__builtin_amdgcn_update_dpp(
      0, __float_as_int(x), 0x101, 0xF, 0xF, true));   // row_shl:1, zero-bound
}

__device__ __forceinline__ float ad4(const float4 a, const float4 b) {
  return fabsf(a.x - b.x) + fabsf(a.y - b.y) + fabsf(a.z - b.z) + fabsf(a.w - b.w);
}

// horizontal 3-tap for one tile row; halos via DPP (zero at segment ends)
__device__ __forceinline__ void hrow4(const float f[4], float h[4]) {
  const float l = dpp_left(f[3]);
  const float r = dpp_right(f[0]);
  h[0] = fmaf(KW1, l + f[1], f[0]);
  h[1] = fmaf(KW1, f[0] + f[2], f[1]);
  h[2] = fmaf(KW1, f[1] + f[3], f[2]);
  h[3] = fmaf(KW1, f[2] + r, f[3]);
}

// Core of one half-step: h of prev field (DPP), hm/hp from raw halo windows,
// vert rows 0,3 + publish them. Rows 1,2 are deferred to after the barrier.
__device__ __forceinline__ void phase_core(
    const float prev[4][4], float ph[4][4],
    const float cf0[4], const float cf3[4],
    float2 mA, float4 mB, float2 mC, float2 pA, float4 pB, float2 pC,
    float* __restrict__ RT_wr, float* __restrict__ RB_wr, int wb,
    float out0[4], float out3[4]) {
  hrow4(prev[0], ph[0]); hrow4(prev[1], ph[1]);
  hrow4(prev[2], ph[2]); hrow4(prev[3], ph[3]);
  float hm[4], hp[4];
  hm[0] = fmaf(KW1, mA.y + mB.y, mB.x);
  hm[1] = fmaf(KW1, mB.x + mB.z, mB.y);
  hm[2] = fmaf(KW1, mB.y + mB.w, mB.z);
  hm[3] = fmaf(KW1, mB.z + mC.x, mB.w);
  hp[0] = fmaf(KW1, pA.y + pB.y, pB.x);
  hp[1] = fmaf(KW1, pB.x + pB.z, pB.y);
  hp[2] = fmaf(KW1, pB.y + pB.w, pB.z);
  hp[3] = fmaf(KW1, pB.z + pC.x, pB.w);
#pragma unroll
  for (int j = 0; j < 4; ++j)
    out0[j] = cf0[j] * __builtin_amdgcn_rcpf(fmaf(KW1, hm[j] + ph[1][j], ph[0][j]));
#pragma unroll
  for (int j = 0; j < 4; ++j)
    out3[j] = cf3[j] * __builtin_amdgcn_rcpf(fmaf(KW1, ph[2][j] + hp[j], ph[3][j]));
  *(float4*)&RT_wr[wb] = make_float4(out0[0], out0[1], out0[2], out0[3]);
  *(float4*)&RB_wr[wb] = make_float4(out3[0], out3[1], out3[2], out3[3]);
}

// ws layout (floats): pc[0..16) gc[16..32) cost[32..48) tvx[48..64) tvy[64..80)
// counter: dword at byte offset 384, memset to 0 pre-launch.
__global__ __launch_bounds__(256) void fused_kernel(
    const float* __restrict__ pred, const float* __restrict__ gt,
    float* __restrict__ ws, const int* __restrict__ epoch,
    const int* __restrict__ max_epoch, float* __restrict__ out,
    unsigned int* __restrict__ cnt) {
  __shared__ float RTu[18 * RP2], RBu[18 * RP2];  // u raw edge rows (top/bottom)
  __shared__ float RTv[18 * RP2], RBv[18 * RP2];  // v raw edge rows
  __shared__ float rbuf[24];

  const int b = blockIdx.x;
  const int t = threadIdx.x;
  const int tyg = t >> 4, tx = t & 15;  // tile coords; wave = 4 tile-rows
  const int y0 = tyg * 4, x0 = tx * 4;

  // zero exchange arrays (boundary slots 0/17 and halo cols stay zero forever)
  for (int i = t; i < 18 * RP2; i += 256) {
    RTu[i] = 0.f; RBu[i] = 0.f; RTv[i] = 0.f; RBv[i] = 0.f;
  }

  // ---- prologue: pool own 16x16 source patch + counts + TV ----
  const float* pb = pred + b * 65536;
  const float* gb = gt + b * 65536;
  const int sr0 = 4 * y0, sc0 = 4 * x0;

  float pd[4][4], gd[4][4];
  float4 pr0, pr1, pr2, pr3;
  float spraw = 0.f, sgraw = 0.f, sx = 0.f, sy = 0.f;
#pragma unroll
  for (int i = 0; i < 4; ++i) {
    float a0 = 0.f, a1 = 0.f, a2 = 0.f, a3 = 0.f;
    float c0 = 0.f, c1 = 0.f, c2 = 0.f, c3 = 0.f;
#pragma unroll 1
    for (int rr = 0; rr < 4; ++rr) {
      const int r = i * 4 + rr;
      const float* prow = pb + (sr0 + r) * 256 + sc0;
      const float4 q0 = *(const float4*)(prow);
      const float4 q1 = *(const float4*)(prow + 4);
      const float4 q2 = *(const float4*)(prow + 8);
      const float4 q3 = *(const float4*)(prow + 12);
      const float s0 = (q0.x + q0.y) + (q0.z + q0.w);
      const float s1 = (q1.x + q1.y) + (q1.z + q1.w);
      const float s2 = (q2.x + q2.y) + (q2.z + q2.w);
      const float s3 = (q3.x + q3.y) + (q3.z + q3.w);
      a0 += s0; a1 += s1; a2 += s2; a3 += s3;
      spraw += (s0 + s1) + (s2 + s3);
      sx += fabsf(q0.y - q0.x) + fabsf(q0.z - q0.y) + fabsf(q0.w - q0.z)
          + fabsf(q1.x - q0.w)
          + fabsf(q1.y - q1.x) + fabsf(q1.z - q1.y) + fabsf(q1.w - q1.z)
          + fabsf(q2.x - q1.w)
          + fabsf(q2.y - q2.x) + fabsf(q2.z - q2.y) + fabsf(q2.w - q2.z)
          + fabsf(q3.x - q2.w)
          + fabsf(q3.y - q3.x) + fabsf(q3.z - q3.y) + fabsf(q3.w - q3.z);
      const float nf = dpp_right(q0.x);  // right nbr's first col
      if (tx < 15) sx += fabsf(nf - q3.w);
      if (r > 0) sy += ad4(q0, pr0) + ad4(q1, pr1) + ad4(q2, pr2) + ad4(q3, pr3);
      pr0 = q0; pr1 = q1; pr2 = q2; pr3 = q3;
      const float* grow = gb + (sr0 + r) * 256 + sc0;
      const float4 g0 = *(const float4*)(grow);
      const float4 g1 = *(const float4*)(grow + 4);
      const float4 g2 = *(const float4*)(grow + 8);
      const float4 g3 = *(const float4*)(grow + 12);
      const float u0 = (g0.x + g0.y) + (g0.z + g0.w);
      const float u1 = (g1.x + g1.y) + (g1.z + g1.w);
      const float u2 = (g2.x + g2.y) + (g2.z + g2.w);
      const float u3 = (g3.x + g3.y) + (g3.z + g3.w);
      c0 += u0; c1 += u1; c2 += u2; c3 += u3;
      sgraw += (u0 + u1) + (u2 + u3);
    }
    pd[i][0] = a0; pd[i][1] = a1; pd[i][2] = a2; pd[i][3] = a3;
    gd[i][0] = c0; gd[i][1] = c1; gd[i][2] = c2; gd[i][3] = c3;
  }
  if (tyg < 15) {  // dy boundary pair (rows sr0+15, sr0+16)
    const float* prow = pb + (sr0 + 16) * 256 + sc0;
    sy += ad4(*(const float4*)(prow), pr0) + ad4(*(const float4*)(prow + 4), pr1)
        + ad4(*(const float4*)(prow + 8), pr2) + ad4(*(const float4*)(prow + 12), pr3);
  }

  float spd = 0.f, sgd = 0.f;
#pragma unroll
  for (int i = 0; i < 4; ++i)
#pragma unroll
    for (int j = 0; j < 4; ++j) {
      pd[i][j] = fmaxf(pd[i][j] * 0.0625f, 0.f); spd += pd[i][j];
      gd[i][j] = fmaxf(gd[i][j] * 0.0625f, 0.f); sgd += gd[i][j];
    }

  // block-reduce 6 values over 4 waves
  float r0 = spraw, r1 = sgraw, r2 = spd, r3 = sgd, r4 = sx, r5 = sy;
#pragma unroll
  for (int o = 32; o > 0; o >>= 1) {
    r0 += __shfl_down(r0, o); r1 += __shfl_down(r1, o);
    r2 += __shfl_down(r2, o); r3 += __shfl_down(r3, o);
    r4 += __shfl_down(r4, o); r5 += __shfl_down(r5, o);
  }
  if ((t & 63) == 0) {
    const int w = t >> 6;
    rbuf[w * 6 + 0] = r0; rbuf[w * 6 + 1] = r1; rbuf[w * 6 + 2] = r2;
    rbuf[w * 6 + 3] = r3; rbuf[w * 6 + 4] = r4; rbuf[w * 6 + 5] = r5;
  }
  __syncthreads();
  if (t == 0) {
    float a0 = 0, a1 = 0, a2 = 0, a3 = 0, a4 = 0, a5 = 0;
    for (int w = 0; w < 4; ++w) {
      a0 += rbuf[w * 6 + 0]; a1 += rbuf[w * 6 + 1]; a2 += rbuf[w * 6 + 2];
      a3 += rbuf[w * 6 + 3]; a4 += rbuf[w * 6 + 4]; a5 += rbuf[w * 6 + 5];
    }
    ws[b] = a0; ws[16 + b] = a1; ws[48 + b] = a4; ws[64 + b] = a5;
    rbuf[0] = a2; rbuf[1] = a3;
  }
  __syncthreads();
  const float Sp = rbuf[0], Sg = rbuf[1];

  float av[4][4], bv[4][4];
#pragma unroll
  for (int i = 0; i < 4; ++i)
#pragma unroll
    for (int j = 0; j < 4; ++j) {
      av[i][j] = (Sp > 0.f) ? (pd[i][j] / Sp) : (1.f / 4096.f);
      bv[i][j] = (Sg > 0.f) ? (gd[i][j] / Sg) : (1.f / 4096.f);
    }

  // ---- Sinkhorn ----
  const int rbb = tyg * RP2 + x0 + 2;        // halo window base (above nbr)
  const int rtb = (tyg + 2) * RP2 + x0 + 2;  // halo window base (below nbr)
  const int wb  = (1 + tyg) * RP2 + 4 + x0;  // own raw-row slot (16B aligned)

  float uu[4][4], vv[4][4], uh[4][4], vh[4][4];
#pragma unroll
  for (int i = 0; i < 4; ++i)
#pragma unroll
    for (int j = 0; j < 4; ++j) vv[i][j] = 1.f;
  *(float4*)&RTv[wb] = make_float4(1.f, 1.f, 1.f, 1.f);
  *(float4*)&RBv[wb] = make_float4(1.f, 1.f, 1.f, 1.f);
  __syncthreads();

#pragma unroll 1
  for (int it = 0; it < 50; ++it) {
    {  // u-phase: u = a / (K v); reads v arrays, writes u arrays
      const float2 mA = *(const float2*)&RBv[rbb];
      const float4 mB = *(const float4*)&RBv[rbb + 2];
      const float2 mC = *(const float2*)&RBv[rbb + 6];
      const float2 pA = *(const float2*)&RTv[rtb];
      const float4 pB = *(const float4*)&RTv[rtb + 2];
      const float2 pC = *(const float2*)&RTv[rtb + 6];
      if (it != 0) {  // deferred v interior (thread-local, overlaps reads)
#pragma unroll
        for (int j = 0; j < 4; ++j) {
          vv[1][j] = bv[1][j] * __builtin_amdgcn_rcpf(fmaf(KW1, uh[0][j] + uh[2][j], uh[1][j]));
          vv[2][j] = bv[2][j] * __builtin_amdgcn_rcpf(fmaf(KW1, uh[1][j] + uh[3][j], uh[2][j]));
        }
      }
      phase_core(vv, vh, av[0], av[3], mA, mB, mC, pA, pB, pC,
                 RTu, RBu, wb, uu[0], uu[3]);
    }
    __syncthreads();
    {  // v-phase: v = b / (K u)
      const float2 mA = *(const float2*)&RBu[rbb];
      const float4 mB = *(const float4*)&RBu[rbb + 2];
      const float2 mC = *(const float2*)&RBu[rbb + 6];
      const float2 pA = *(const float2*)&RTu[rtb];
      const float4 pB = *(const float4*)&RTu[rtb + 2];
      const float2 pC = *(const float2*)&RTu[rtb + 6];
#pragma unroll
      for (int j = 0; j < 4; ++j) {  // deferred u interior
        uu[1][j] = av[1][j] * __builtin_amdgcn_rcpf(fmaf(KW1, vh[0][j] + vh[2][j], vh[1][j]));
        uu[2][j] = av[2][j] * __builtin_amdgcn_rcpf(fmaf(KW1, vh[1][j] + vh[3][j], vh[2][j]));
      }
      phase_core(uu, uh, bv[0], bv[3], mA, mB, mC, pA, pB, pC,
                 RTv, RBv, wb, vv[0], vv[3]);
    }
    __syncthreads();
  }

  // finish deferred final-v interior
#pragma unroll
  for (int j = 0; j < 4; ++j) {
    vv[1][j] = bv[1][j] * __builtin_amdgcn_rcpf(fmaf(KW1, uh[0][j] + uh[2][j], uh[1][j]));
    vv[2][j] = bv[2][j] * __builtin_amdgcn_rcpf(fmaf(KW1, uh[1][j] + uh[3][j], uh[2][j]));
  }

  // ---- cost epilogue: 6x6 ring of final v (K.M not separable) ----
  float c = 0.f;
  {
    const float2 mA = *(const float2*)&RBv[rbb];   // row y0-1 window
    const float4 mB = *(const float4*)&RBv[rbb + 2];
    const float2 mC = *(const float2*)&RBv[rbb + 6];
    const float2 pA = *(const float2*)&RTv[rtb];   // row y0+4 window
    const float4 pB = *(const float4*)&RTv[rtb + 2];
    const float2 pC = *(const float2*)&RTv[rtb + 6];
    float W[6][6];
    W[0][0] = mA.y; W[0][1] = mB.x; W[0][2] = mB.y;
    W[0][3] = mB.z; W[0][4] = mB.w; W[0][5] = mC.x;
    W[5][0] = pA.y; W[5][1] = pB.x; W[5][2] = pB.y;
    W[5][3] = pB.z; W[5][4] = pB.w; W[5][5] = pC.x;
#pragma unroll
    for (int i = 0; i < 4; ++i) {
      W[1 + i][0] = dpp_left(vv[i][3]);   // zero at tx==0 boundary
      W[1 + i][5] = dpp_right(vv[i][0]);  // zero at tx==15 boundary
#pragma unroll
      for (int j = 0; j < 4; ++j) W[1 + i][1 + j] = vv[i][j];
    }
#pragma unroll
    for (int i = 0; i < 4; ++i)
#pragma unroll
      for (int j = 0; j < 4; ++j) {
        const float e = (W[i][j + 1] + W[i + 2][j + 1])
                      + (W[i + 1][j] + W[i + 1][j + 2]);
        const float d = (W[i][j] + W[i][j + 2])
                      + (W[i + 2][j] + W[i + 2][j + 2]);
        c += uu[i][j] * fmaf(MW2, d, KW1 * e);
      }
  }
#pragma unroll
  for (int o = 32; o > 0; o >>= 1) c += __shfl_down(c, o);
  if ((t & 63) == 0) rbuf[t >> 6] = c;
  __syncthreads();
  if (t == 0) {
    ws[32 + b] = rbuf[0] + rbuf[1] + rbuf[2] + rbuf[3];
    // ---- ticket: last block finalizes ----
    __threadfence();
    const unsigned int old = atomicAdd(cnt, 1u);
    if (old == 15u) {
      __threadfence();
      float lc = 0.f, lot = 0.f, tvx = 0.f, tvy = 0.f;
      for (int k = 0; k < 16; ++k) {
        const float p  = __hip_atomic_load(&ws[k],      __ATOMIC_RELAXED, __HIP_MEMORY_SCOPE_AGENT);
        const float g  = __hip_atomic_load(&ws[16 + k], __ATOMIC_RELAXED, __HIP_MEMORY_SCOPE_AGENT);
        const float ct = __hip_atomic_load(&ws[32 + k], __ATOMIC_RELAXED, __HIP_MEMORY_SCOPE_AGENT);
        const float x  = __hip_atomic_load(&ws[48 + k], __ATOMIC_RELAXED, __HIP_MEMORY_SCOPE_AGENT);
        const float y  = __hip_atomic_load(&ws[64 + k], __ATOMIC_RELAXED, __HIP_MEMORY_SCOPE_AGENT);
        lc += fabsf(p - g); lot += ct; tvx += x; tvy += y;
      }
      int me = max_epoch[0]; if (me < 1) me = 1;
      const float tt = (float)epoch[0] / (float)me;
      const float ltv = tvx / (16.f * 256.f * 255.f) + tvy / (16.f * 255.f * 256.f);
      out[0] = lc * (1.f / 16.f) + tt * (lot * (1.f / 16.f)) + tt * ltv;
    }
  }
}

extern "C" void kernel_launch(void* const* d_in, const int* in_sizes, int n_in,
                              void* d_out, int out_size, void* d_ws, size_t ws_size,
                              hipStream_t stream) {
  const float* pred = (const float*)d_in[0];
  const float* gt   = (const float*)d_in[1];
  const int* epoch  = (const int*)d_in[2];
  const int* max_ep = (const int*)d_in[3];
  float* out = (float*)d_out;
  float* ws  = (float*)d_ws;
  unsigned int* cnt = (unsigned int*)((char*)d_ws + 384);

  hipMemsetAsync(cnt, 0, 4, stream);
  fused_kernel<<<dim3(16), dim3(256), 0, stream>>>(pred, gt, ws, epoch,
                                                   max_ep, out, cnt);
}

// Round 7
// 111.485 us; speedup vs baseline: 2.7951x; 1.0838x over previous
//
#include <hip/hip_runtime.h>
#include <math.h>

// ---------------------------------------------------------------------------
// CurriculumLoss: l_count + t*(OT via Sinkhorn on 64x64 downsample) + t*TV
//
// K = exp(-M/0.05) underflows to 0 in f32 for M >= 8; the surviving 9-tap
// kernel is exactly separable: (1, e^-20) (x) (1, e^-20). Sinkhorn becomes
// 100 half-steps of a separable 3x3 stencil + rcp on a 64x64 field.
//
// R7: SPLIT PROLOGUE. R4-R6 stagnated at ~65 us across three different loop
// implementations -> the constant was the prologue: 512 KB of pred+gt per
// block streamed by only 4 waves (no MLP to hide latency) ~ 20-30 us.
//  - prep_kernel: 256 blocks x 256 threads (full chip) pools 4x4 + relu,
//    computes count sums + TV partials, writes pooled fields + partials to ws.
//  - sink_kernel: 16 blocks x 256 threads loads 32 KB of L2-hot pooled field,
//    runs the UNCHANGED R6 Sinkhorn loop (DPP horizontal halos, raw-edge-row
//    vertical halos, deferred interior), cooperative ticket finalize.
//  - Fallback to the R6 monolith if ws_size is too small.
//
// ws layout (floats):
//   [0..256)    pc partials (per prep block)     [256..512)  gc partials
//   [512..768)  tvx partials                     [768..1024) tvy partials
//   [1024..1040) cost per image
//   cnt dword at float idx 1040 (byte 4160)
//   [2048..67584)   pooled relu'd pred fields (16 x 4096)
//   [67584..133120) pooled relu'd gt fields
// ---------------------------------------------------------------------------

#define KW1 2.0611536224385578e-09f  // exp(-20)
#define MW2 8.4967085105831778e-18f  // 2*exp(-40)
#define RP2 72                       // row storage: cols -4..67 at +4
#define PDOFF 2048
#define GDOFF 67584

// DPP lane shifts within 16-lane rows (= tile-row segments).
__device__ __forceinline__ float dpp_left(float x) {   // lane tx-1's value; 0 at tx==0
  return __int_as_float(__builtin_amdgcn_update_dpp(
      0, __float_as_int(x), 0x111, 0xF, 0xF, true));   // row_shr:1, zero-bound
}
__device__ __forceinline__ float dpp_right(float x) {  // lane tx+1's value; 0 at tx==15
  return __int_as_float(__builtin_amdgcn_update_dpp(
      0, __float_as_int(x), 0x101, 0xF, 0xF, true));   // row_shl:1, zero-bound
}

__device__ __forceinline__ float ad4(const float4 a, const float4 b) {
  return fabsf(a.x - b.x) + fabsf(a.y - b.y) + fabsf(a.z - b.z) + fabsf(a.w - b.w);
}

__device__ __forceinline__ float agent_ld(const float* p) {
  return __hip_atomic_load(p, __ATOMIC_RELAXED, __HIP_MEMORY_SCOPE_AGENT);
}

// horizontal 3-tap for one tile row; halos via DPP (zero at segment ends)
__device__ __forceinline__ void hrow4(const float f[4], float h[4]) {
  const float l = dpp_left(f[3]);
  const float r = dpp_right(f[0]);
  h[0] = fmaf(KW1, l + f[1], f[0]);
  h[1] = fmaf(KW1, f[0] + f[2], f[1]);
  h[2] = fmaf(KW1, f[1] + f[3], f[2]);
  h[3] = fmaf(KW1, f[2] + r, f[3]);
}

// Core of one half-step: h of prev field (DPP), hm/hp from raw halo windows,
// vert rows 0,3 + publish them. Rows 1,2 deferred past the barrier.
__device__ __forceinline__ void phase_core(
    const float prev[4][4], float ph[4][4],
    const float cf0[4], const float cf3[4],
    float2 mA, float4 mB, float2 mC, float2 pA, float4 pB, float2 pC,
    float* __restrict__ RT_wr, float* __restrict__ RB_wr, int wb,
    float out0[4], float out3[4]) {
  hrow4(prev[0], ph[0]); hrow4(prev[1], ph[1]);
  hrow4(prev[2], ph[2]); hrow4(prev[3], ph[3]);
  float hm[4], hp[4];
  hm[0] = fmaf(KW1, mA.y + mB.y, mB.x);
  hm[1] = fmaf(KW1, mB.x + mB.z, mB.y);
  hm[2] = fmaf(KW1, mB.y + mB.w, mB.z);
  hm[3] = fmaf(KW1, mB.z + mC.x, mB.w);
  hp[0] = fmaf(KW1, pA.y + pB.y, pB.x);
  hp[1] = fmaf(KW1, pB.x + pB.z, pB.y);
  hp[2] = fmaf(KW1, pB.y + pB.w, pB.z);
  hp[3] = fmaf(KW1, pB.z + pC.x, pB.w);
#pragma unroll
  for (int j = 0; j < 4; ++j)
    out0[j] = cf0[j] * __builtin_amdgcn_rcpf(fmaf(KW1, hm[j] + ph[1][j], ph[0][j]));
#pragma unroll
  for (int j = 0; j < 4; ++j)
    out3[j] = cf3[j] * __builtin_amdgcn_rcpf(fmaf(KW1, ph[2][j] + hp[j], ph[3][j]));
  *(float4*)&RT_wr[wb] = make_float4(out0[0], out0[1], out0[2], out0[3]);
  *(float4*)&RB_wr[wb] = make_float4(out3[0], out3[1], out3[2], out3[3]);
}

// ======================= prep: full-chip pooling + TV =======================
__global__ __launch_bounds__(256) void prep_kernel(
    const float* __restrict__ pred, const float* __restrict__ gt,
    float* __restrict__ ws) {
  __shared__ float rbuf[16];
  const int g = blockIdx.x;
  const int im = g >> 4, band = g & 15;   // 16 source rows per block
  const int t = threadIdx.x;
  const int ppy = t >> 6, ppx = t & 63;   // wave = one patch-row (64 patches)
  const float* pb = pred + im * 65536;
  const float* gb = gt + im * 65536;
  const int sr0 = band * 16 + ppy * 4;
  const int c0 = ppx * 4;

  float4 q[4];
  float ps = 0.f, gs = 0.f, sx = 0.f, sy = 0.f;
#pragma unroll
  for (int r = 0; r < 4; ++r) {
    q[r] = *(const float4*)(pb + (sr0 + r) * 256 + c0);
    const float4 e = *(const float4*)(gb + (sr0 + r) * 256 + c0);
    ps += (q[r].x + q[r].y) + (q[r].z + q[r].w);
    gs += (e.x + e.y) + (e.z + e.w);
    sx += fabsf(q[r].y - q[r].x) + fabsf(q[r].z - q[r].y) + fabsf(q[r].w - q[r].z);
    const float nf = __shfl_down(q[r].x, 1);  // right patch's col 0 (same wave)
    if (ppx < 63) sx += fabsf(nf - q[r].w);
  }
  sy += ad4(q[1], q[0]) + ad4(q[2], q[1]) + ad4(q[3], q[2]);
  if (sr0 + 4 < 256) {                        // dy boundary to next patch row
    const float4 qn = *(const float4*)(pb + (sr0 + 4) * 256 + c0);
    sy += ad4(qn, q[3]);
  }
  // pooled relu'd values
  const int prow = band * 4 + ppy;
  ws[PDOFF + im * 4096 + prow * 64 + ppx] = fmaxf(ps * 0.0625f, 0.f);
  ws[GDOFF + im * 4096 + prow * 64 + ppx] = fmaxf(gs * 0.0625f, 0.f);

  // block-reduce 4 sums -> per-block partials
  float r0 = ps, r1 = gs, r2 = sx, r3 = sy;
#pragma unroll
  for (int o = 32; o > 0; o >>= 1) {
    r0 += __shfl_down(r0, o); r1 += __shfl_down(r1, o);
    r2 += __shfl_down(r2, o); r3 += __shfl_down(r3, o);
  }
  if ((t & 63) == 0) {
    const int w = t >> 6;
    rbuf[w * 4 + 0] = r0; rbuf[w * 4 + 1] = r1;
    rbuf[w * 4 + 2] = r2; rbuf[w * 4 + 3] = r3;
  }
  __syncthreads();
  if (t == 0) {
    float a0 = 0, a1 = 0, a2 = 0, a3 = 0;
    for (int w = 0; w < 4; ++w) {
      a0 += rbuf[w * 4]; a1 += rbuf[w * 4 + 1];
      a2 += rbuf[w * 4 + 2]; a3 += rbuf[w * 4 + 3];
    }
    ws[g] = a0; ws[256 + g] = a1; ws[512 + g] = a2; ws[768 + g] = a3;
  }
}

// ======================= sinkhorn on pooled fields ==========================
__global__ __launch_bounds__(256) void sink_kernel(
    float* __restrict__ ws, const int* __restrict__ epoch,
    const int* __restrict__ max_epoch, float* __restrict__ out,
    unsigned int* __restrict__ cnt) {
  __shared__ float RTu[18 * RP2], RBu[18 * RP2];
  __shared__ float RTv[18 * RP2], RBv[18 * RP2];
  __shared__ float rbuf[24];
  __shared__ int lastflag;

  const int b = blockIdx.x;
  const int t = threadIdx.x;
  const int tyg = t >> 4, tx = t & 15;
  const int y0 = tyg * 4, x0 = tx * 4;

  for (int i = t; i < 18 * RP2; i += 256) {
    RTu[i] = 0.f; RBu[i] = 0.f; RTv[i] = 0.f; RBv[i] = 0.f;
  }

  // load pooled fields (L2-hot, written by prep_kernel)
  float pdv[4][4], gdv[4][4];
  float spd = 0.f, sgd = 0.f;
#pragma unroll
  for (int i = 0; i < 4; ++i) {
    const float4 qa = *(const float4*)&ws[PDOFF + b * 4096 + (y0 + i) * 64 + x0];
    pdv[i][0] = qa.x; pdv[i][1] = qa.y; pdv[i][2] = qa.z; pdv[i][3] = qa.w;
    spd += (qa.x + qa.y) + (qa.z + qa.w);
    const float4 qb = *(const float4*)&ws[GDOFF + b * 4096 + (y0 + i) * 64 + x0];
    gdv[i][0] = qb.x; gdv[i][1] = qb.y; gdv[i][2] = qb.z; gdv[i][3] = qb.w;
    sgd += (qb.x + qb.y) + (qb.z + qb.w);
  }
  float r2 = spd, r3 = sgd;
#pragma unroll
  for (int o = 32; o > 0; o >>= 1) { r2 += __shfl_down(r2, o); r3 += __shfl_down(r3, o); }
  if ((t & 63) == 0) { rbuf[(t >> 6) * 2] = r2; rbuf[(t >> 6) * 2 + 1] = r3; }
  __syncthreads();
  if (t == 0) {
    rbuf[16] = rbuf[0] + rbuf[2] + rbuf[4] + rbuf[6];
    rbuf[17] = rbuf[1] + rbuf[3] + rbuf[5] + rbuf[7];
  }
  __syncthreads();
  const float Sp = rbuf[16], Sg = rbuf[17];

  float av[4][4], bv[4][4];
#pragma unroll
  for (int i = 0; i < 4; ++i)
#pragma unroll
    for (int j = 0; j < 4; ++j) {
      av[i][j] = (Sp > 0.f) ? (pdv[i][j] / Sp) : (1.f / 4096.f);
      bv[i][j] = (Sg > 0.f) ? (gdv[i][j] / Sg) : (1.f / 4096.f);
    }

  // ---- Sinkhorn loop (identical to R6) ----
  const int rbb = tyg * RP2 + x0 + 2;
  const int rtb = (tyg + 2) * RP2 + x0 + 2;
  const int wb  = (1 + tyg) * RP2 + 4 + x0;

  float uu[4][4], vv[4][4], uh[4][4], vh[4][4];
#pragma unroll
  for (int i = 0; i < 4; ++i)
#pragma unroll
    for (int j = 0; j < 4; ++j) vv[i][j] = 1.f;
  *(float4*)&RTv[wb] = make_float4(1.f, 1.f, 1.f, 1.f);
  *(float4*)&RBv[wb] = make_float4(1.f, 1.f, 1.f, 1.f);
  __syncthreads();

#pragma unroll 1
  for (int it = 0; it < 50; ++it) {
    {  // u-phase
      const float2 mA = *(const float2*)&RBv[rbb];
      const float4 mB = *(const float4*)&RBv[rbb + 2];
      const float2 mC = *(const float2*)&RBv[rbb + 6];
      const float2 pA = *(const float2*)&RTv[rtb];
      const float4 pB = *(const float4*)&RTv[rtb + 2];
      const float2 pC = *(const float2*)&RTv[rtb + 6];
      if (it != 0) {
#pragma unroll
        for (int j = 0; j < 4; ++j) {
          vv[1][j] = bv[1][j] * __builtin_amdgcn_rcpf(fmaf(KW1, uh[0][j] + uh[2][j], uh[1][j]));
          vv[2][j] = bv[2][j] * __builtin_amdgcn_rcpf(fmaf(KW1, uh[1][j] + uh[3][j], uh[2][j]));
        }
      }
      phase_core(vv, vh, av[0], av[3], mA, mB, mC, pA, pB, pC,
                 RTu, RBu, wb, uu[0], uu[3]);
    }
    __syncthreads();
    {  // v-phase
      const float2 mA = *(const float2*)&RBu[rbb];
      const float4 mB = *(const float4*)&RBu[rbb + 2];
      const float2 mC = *(const float2*)&RBu[rbb + 6];
      const float2 pA = *(const float2*)&RTu[rtb];
      const float4 pB = *(const float4*)&RTu[rtb + 2];
      const float2 pC = *(const float2*)&RTu[rtb + 6];
#pragma unroll
      for (int j = 0; j < 4; ++j) {
        uu[1][j] = av[1][j] * __builtin_amdgcn_rcpf(fmaf(KW1, vh[0][j] + vh[2][j], vh[1][j]));
        uu[2][j] = av[2][j] * __builtin_amdgcn_rcpf(fmaf(KW1, vh[1][j] + vh[3][j], vh[2][j]));
      }
      phase_core(uu, uh, bv[0], bv[3], mA, mB, mC, pA, pB, pC,
                 RTv, RBv, wb, vv[0], vv[3]);
    }
    __syncthreads();
  }
#pragma unroll
  for (int j = 0; j < 4; ++j) {
    vv[1][j] = bv[1][j] * __builtin_amdgcn_rcpf(fmaf(KW1, uh[0][j] + uh[2][j], uh[1][j]));
    vv[2][j] = bv[2][j] * __builtin_amdgcn_rcpf(fmaf(KW1, uh[1][j] + uh[3][j], uh[2][j]));
  }

  // ---- cost epilogue ----
  float c = 0.f;
  {
    const float2 mA = *(const float2*)&RBv[rbb];
    const float4 mB = *(const float4*)&RBv[rbb + 2];
    const float2 mC = *(const float2*)&RBv[rbb + 6];
    const float2 pA = *(const float2*)&RTv[rtb];
    const float4 pB = *(const float4*)&RTv[rtb + 2];
    const float2 pC = *(const float2*)&RTv[rtb + 6];
    float W[6][6];
    W[0][0] = mA.y; W[0][1] = mB.x; W[0][2] = mB.y;
    W[0][3] = mB.z; W[0][4] = mB.w; W[0][5] = mC.x;
    W[5][0] = pA.y; W[5][1] = pB.x; W[5][2] = pB.y;
    W[5][3] = pB.z; W[5][4] = pB.w; W[5][5] = pC.x;
#pragma unroll
    for (int i = 0; i < 4; ++i) {
      W[1 + i][0] = dpp_left(vv[i][3]);
      W[1 + i][5] = dpp_right(vv[i][0]);
#pragma unroll
      for (int j = 0; j < 4; ++j) W[1 + i][1 + j] = vv[i][j];
    }
#pragma unroll
    for (int i = 0; i < 4; ++i)
#pragma unroll
      for (int j = 0; j < 4; ++j) {
        const float e = (W[i][j + 1] + W[i + 2][j + 1])
                      + (W[i + 1][j] + W[i + 1][j + 2]);
        const float d = (W[i][j] + W[i][j + 2])
                      + (W[i + 2][j] + W[i + 2][j + 2]);
        c += uu[i][j] * fmaf(MW2, d, KW1 * e);
      }
  }
#pragma unroll
  for (int o = 32; o > 0; o >>= 1) c += __shfl_down(c, o);
  if ((t & 63) == 0) rbuf[t >> 6] = c;
  __syncthreads();
  if (t == 0) {
    ws[1024 + b] = rbuf[0] + rbuf[1] + rbuf[2] + rbuf[3];
    __threadfence();
    const unsigned int old = atomicAdd(cnt, 1u);
    lastflag = (old == 15u) ? 1 : 0;
  }
  __syncthreads();

  // ---- cooperative finalize by the last block ----
  if (lastflag) {
    __threadfence();
    float myPc = agent_ld(&ws[t]);
    float myGc = agent_ld(&ws[256 + t]);
    float myTx = agent_ld(&ws[512 + t]);
    float myTy = agent_ld(&ws[768 + t]);
#pragma unroll
    for (int o = 8; o > 0; o >>= 1) {  // per-image partial groups of 16
      myPc += __shfl_down(myPc, o, 16);
      myGc += __shfl_down(myGc, o, 16);
    }
    float d = ((t & 15) == 0) ? fabsf(myPc - myGc) : 0.f;
    float ct = (t < 16) ? agent_ld(&ws[1024 + t]) : 0.f;
#pragma unroll
    for (int o = 32; o > 0; o >>= 1) {
      d += __shfl_down(d, o); ct += __shfl_down(ct, o);
      myTx += __shfl_down(myTx, o); myTy += __shfl_down(myTy, o);
    }
    if ((t & 63) == 0) {
      const int w = t >> 6;
      rbuf[w * 4] = d; rbuf[w * 4 + 1] = ct;
      rbuf[w * 4 + 2] = myTx; rbuf[w * 4 + 3] = myTy;
    }
    __syncthreads();
    if (t == 0) {
      float lc = 0, lot = 0, tvx = 0, tvy = 0;
      for (int w = 0; w < 4; ++w) {
        lc += rbuf[w * 4]; lot += rbuf[w * 4 + 1];
        tvx += rbuf[w * 4 + 2]; tvy += rbuf[w * 4 + 3];
      }
      int me = max_epoch[0]; if (me < 1) me = 1;
      const float tt = (float)epoch[0] / (float)me;
      const float ltv = tvx / (16.f * 256.f * 255.f) + tvy / (16.f * 255.f * 256.f);
      out[0] = lc * (1.f / 16.f) + tt * (lot * (1.f / 16.f)) + tt * ltv;
    }
  }
}

// ================= fallback (R6 monolith) if ws is too small ================
__global__ __launch_bounds__(256) void fused_fallback(
    const float* __restrict__ pred, const float* __restrict__ gt,
    float* __restrict__ ws, const int* __restrict__ epoch,
    const int* __restrict__ max_epoch, float* __restrict__ out,
    unsigned int* __restrict__ cnt) {
  __shared__ float RTu[18 * RP2], RBu[18 * RP2];
  __shared__ float RTv[18 * RP2], RBv[18 * RP2];
  __shared__ float rbuf[24];

  const int b = blockIdx.x;
  const int t = threadIdx.x;
  const int tyg = t >> 4, tx = t & 15;
  const int y0 = tyg * 4, x0 = tx * 4;

  for (int i = t; i < 18 * RP2; i += 256) {
    RTu[i] = 0.f; RBu[i] = 0.f; RTv[i] = 0.f; RBv[i] = 0.f;
  }

  const float* pb = pred + b * 65536;
  const float* gb = gt + b * 65536;
  const int sr0 = 4 * y0, sc0 = 4 * x0;

  float pd[4][4], gd[4][4];
  float4 pr0, pr1, pr2, pr3;
  float spraw = 0.f, sgraw = 0.f, sx = 0.f, sy = 0.f;
#pragma unroll
  for (int i = 0; i < 4; ++i) {
    float a0 = 0.f, a1 = 0.f, a2 = 0.f, a3 = 0.f;
    float c0 = 0.f, c1 = 0.f, c2 = 0.f, c3 = 0.f;
#pragma unroll 1
    for (int rr = 0; rr < 4; ++rr) {
      const int r = i * 4 + rr;
      const float* prow = pb + (sr0 + r) * 256 + sc0;
      const float4 q0 = *(const float4*)(prow);
      const float4 q1 = *(const float4*)(prow + 4);
      const float4 q2 = *(const float4*)(prow + 8);
      const float4 q3 = *(const float4*)(prow + 12);
      const float s0 = (q0.x + q0.y) + (q0.z + q0.w);
      const float s1 = (q1.x + q1.y) + (q1.z + q1.w);
      const float s2 = (q2.x + q2.y) + (q2.z + q2.w);
      const float s3 = (q3.x + q3.y) + (q3.z + q3.w);
      a0 += s0; a1 += s1; a2 += s2; a3 += s3;
      spraw += (s0 + s1) + (s2 + s3);
      sx += fabsf(q0.y - q0.x) + fabsf(q0.z - q0.y) + fabsf(q0.w - q0.z)
          + fabsf(q1.x - q0.w)
          + fabsf(q1.y - q1.x) + fabsf(q1.z - q1.y) + fabsf(q1.w - q1.z)
          + fabsf(q2.x - q1.w)
          + fabsf(q2.y - q2.x) + fabsf(q2.z - q2.y) + fabsf(q2.w - q2.z)
          + fabsf(q3.x - q2.w)
          + fabsf(q3.y - q3.x) + fabsf(q3.z - q3.y) + fabsf(q3.w - q3.z);
      const float nf = dpp_right(q0.x);
      if (tx < 15) sx += fabsf(nf - q3.w);
      if (r > 0) sy += ad4(q0, pr0) + ad4(q1, pr1) + ad4(q2, pr2) + ad4(q3, pr3);
      pr0 = q0; pr1 = q1; pr2 = q2; pr3 = q3;
      const float* grow = gb + (sr0 + r) * 256 + sc0;
      const float4 g0 = *(const float4*)(grow);
      const float4 g1 = *(const float4*)(grow + 4);
      const float4 g2 = *(const float4*)(grow + 8);
      const float4 g3 = *(const float4*)(grow + 12);
      const float u0 = (g0.x + g0.y) + (g0.z + g0.w);
      const float u1 = (g1.x + g1.y) + (g1.z + g1.w);
      const float u2 = (g2.x + g2.y) + (g2.z + g2.w);
      const float u3 = (g3.x + g3.y) + (g3.z + g3.w);
      c0 += u0; c1 += u1; c2 += u2; c3 += u3;
      sgraw += (u0 + u1) + (u2 + u3);
    }
    pd[i][0] = a0; pd[i][1] = a1; pd[i][2] = a2; pd[i][3] = a3;
    gd[i][0] = c0; gd[i][1] = c1; gd[i][2] = c2; gd[i][3] = c3;
  }
  if (tyg < 15) {
    const float* prow = pb + (sr0 + 16) * 256 + sc0;
    sy += ad4(*(const float4*)(prow), pr0) + ad4(*(const float4*)(prow + 4), pr1)
        + ad4(*(const float4*)(prow + 8), pr2) + ad4(*(const float4*)(prow + 12), pr3);
  }

  float spd = 0.f, sgd = 0.f;
#pragma unroll
  for (int i = 0; i < 4; ++i)
#pragma unroll
    for (int j = 0; j < 4; ++j) {
      pd[i][j] = fmaxf(pd[i][j] * 0.0625f, 0.f); spd += pd[i][j];
      gd[i][j] = fmaxf(gd[i][j] * 0.0625f, 0.f); sgd += gd[i][j];
    }

  float r0 = spraw, r1 = sgraw, r2 = spd, r3 = sgd, r4 = sx, r5 = sy;
#pragma unroll
  for (int o = 32; o > 0; o >>= 1) {
    r0 += __shfl_down(r0, o); r1 += __shfl_down(r1, o);
    r2 += __shfl_down(r2, o); r3 += __shfl_down(r3, o);
    r4 += __shfl_down(r4, o); r5 += __shfl_down(r5, o);
  }
  if ((t & 63) == 0) {
    const int w = t >> 6;
    rbuf[w * 6 + 0] = r0; rbuf[w * 6 + 1] = r1; rbuf[w * 6 + 2] = r2;
    rbuf[w * 6 + 3] = r3; rbuf[w * 6 + 4] = r4; rbuf[w * 6 + 5] = r5;
  }
  __syncthreads();
  if (t == 0) {
    float a0 = 0, a1 = 0, a2 = 0, a3 = 0, a4 = 0, a5 = 0;
    for (int w = 0; w < 4; ++w) {
      a0 += rbuf[w * 6 + 0]; a1 += rbuf[w * 6 + 1]; a2 += rbuf[w * 6 + 2];
      a3 += rbuf[w * 6 + 3]; a4 += rbuf[w * 6 + 4]; a5 += rbuf[w * 6 + 5];
    }
    ws[b] = a0; ws[16 + b] = a1; ws[48 + b] = a4; ws[64 + b] = a5;
    rbuf[0] = a2; rbuf[1] = a3;
  }
  __syncthreads();
  const float Sp = rbuf[0], Sg = rbuf[1];

  float av[4][4], bv[4][4];
#pragma unroll
  for (int i = 0; i < 4; ++i)
#pragma unroll
    for (int j = 0; j < 4; ++j) {
      av[i][j] = (Sp > 0.f) ? (pd[i][j] / Sp) : (1.f / 4096.f);
      bv[i][j] = (Sg > 0.f) ? (gd[i][j] / Sg) : (1.f / 4096.f);
    }

  const int rbb = tyg * RP2 + x0 + 2;
  const int rtb = (tyg + 2) * RP2 + x0 + 2;
  const int wb  = (1 + tyg) * RP2 + 4 + x0;

  float uu[4][4], vv[4][4], uh[4][4], vh[4][4];
#pragma unroll
  for (int i = 0; i < 4; ++i)
#pragma unroll
    for (int j = 0; j < 4; ++j) vv[i][j] = 1.f;
  *(float4*)&RTv[wb] = make_float4(1.f, 1.f, 1.f, 1.f);
  *(float4*)&RBv[wb] = make_float4(1.f, 1.f, 1.f, 1.f);
  __syncthreads();

#pragma unroll 1
  for (int it = 0; it < 50; ++it) {
    {
      const float2 mA = *(const float2*)&RBv[rbb];
      const float4 mB = *(const float4*)&RBv[rbb + 2];
      const float2 mC = *(const float2*)&RBv[rbb + 6];
      const float2 pA = *(const float2*)&RTv[rtb];
      const float4 pB = *(const float4*)&RTv[rtb + 2];
      const float2 pC = *(const float2*)&RTv[rtb + 6];
      if (it != 0) {
#pragma unroll
        for (int j = 0; j < 4; ++j) {
          vv[1][j] = bv[1][j] * __builtin_amdgcn_rcpf(fmaf(KW1, uh[0][j] + uh[2][j], uh[1][j]));
          vv[2][j] = bv[2][j] * __builtin_amdgcn_rcpf(fmaf(KW1, uh[1][j] + uh[3][j], uh[2][j]));
        }
      }
      phase_core(vv, vh, av[0], av[3], mA, mB, mC, pA, pB, pC,
                 RTu, RBu, wb, uu[0], uu[3]);
    }
    __syncthreads();
    {
      const float2 mA = *(const float2*)&RBu[rbb];
      const float4 mB = *(const float4*)&RBu[rbb + 2];
      const float2 mC = *(const float2*)&RBu[rbb + 6];
      const float2 pA = *(const float2*)&RTu[rtb];
      const float4 pB = *(const float4*)&RTu[rtb + 2];
      const float2 pC = *(const float2*)&RTu[rtb + 6];
#pragma unroll
      for (int j = 0; j < 4; ++j) {
        uu[1][j] = av[1][j] * __builtin_amdgcn_rcpf(fmaf(KW1, vh[0][j] + vh[2][j], vh[1][j]));
        uu[2][j] = av[2][j] * __builtin_amdgcn_rcpf(fmaf(KW1, vh[1][j] + vh[3][j], vh[2][j]));
      }
      phase_core(uu, uh, bv[0], bv[3], mA, mB, mC, pA, pB, pC,
                 RTv, RBv, wb, vv[0], vv[3]);
    }
    __syncthreads();
  }
#pragma unroll
  for (int j = 0; j < 4; ++j) {
    vv[1][j] = bv[1][j] * __builtin_amdgcn_rcpf(fmaf(KW1, uh[0][j] + uh[2][j], uh[1][j]));
    vv[2][j] = bv[2][j] * __builtin_amdgcn_rcpf(fmaf(KW1, uh[1][j] + uh[3][j], uh[2][j]));
  }

  float c = 0.f;
  {
    const float2 mA = *(const float2*)&RBv[rbb];
    const float4 mB = *(const float4*)&RBv[rbb + 2];
    const float2 mC = *(const float2*)&RBv[rbb + 6];
    const float2 pA = *(const float2*)&RTv[rtb];
    const float4 pB = *(const float4*)&RTv[rtb + 2];
    const float2 pC = *(const float2*)&RTv[rtb + 6];
    float W[6][6];
    W[0][0] = mA.y; W[0][1] = mB.x; W[0][2] = mB.y;
    W[0][3] = mB.z; W[0][4] = mB.w; W[0][5] = mC.x;
    W[5][0] = pA.y; W[5][1] = pB.x; W[5][2] = pB.y;
    W[5][3] = pB.z; W[5][4] = pB.w; W[5][5] = pC.x;
#pragma unroll
    for (int i = 0; i < 4; ++i) {
      W[1 + i][0] = dpp_left(vv[i][3]);
      W[1 + i][5] = dpp_right(vv[i][0]);
#pragma unroll
      for (int j = 0; j < 4; ++j) W[1 + i][1 + j] = vv[i][j];
    }
#pragma unroll
    for (int i = 0; i < 4; ++i)
#pragma unroll
      for (int j = 0; j < 4; ++j) {
        const float e = (W[i][j + 1] + W[i + 2][j + 1])
                      + (W[i + 1][j] + W[i + 1][j + 2]);
        const float d = (W[i][j] + W[i][j + 2])
                      + (W[i + 2][j] + W[i + 2][j + 2]);
        c += uu[i][j] * fmaf(MW2, d, KW1 * e);
      }
  }
#pragma unroll
  for (int o = 32; o > 0; o >>= 1) c += __shfl_down(c, o);
  if ((t & 63) == 0) rbuf[t >> 6] = c;
  __syncthreads();
  if (t == 0) {
    ws[32 + b] = rbuf[0] + rbuf[1] + rbuf[2] + rbuf[3];
    __threadfence();
    const unsigned int old = atomicAdd(cnt, 1u);
    if (old == 15u) {
      __threadfence();
      float lc = 0.f, lot = 0.f, tvx = 0.f, tvy = 0.f;
      for (int k = 0; k < 16; ++k) {
        const float p = agent_ld(&ws[k]);
        const float g = agent_ld(&ws[16 + k]);
        const float ct = agent_ld(&ws[32 + k]);
        const float x = agent_ld(&ws[48 + k]);
        const float y = agent_ld(&ws[64 + k]);
        lc += fabsf(p - g); lot += ct; tvx += x; tvy += y;
      }
      int me = max_epoch[0]; if (me < 1) me = 1;
      const float tt = (float)epoch[0] / (float)me;
      const float ltv = tvx / (16.f * 256.f * 255.f) + tvy / (16.f * 255.f * 256.f);
      out[0] = lc * (1.f / 16.f) + tt * (lot * (1.f / 16.f)) + tt * ltv;
    }
  }
}

extern "C" void kernel_launch(void* const* d_in, const int* in_sizes, int n_in,
                              void* d_out, int out_size, void* d_ws, size_t ws_size,
                              hipStream_t stream) {
  const float* pred = (const float*)d_in[0];
  const float* gt   = (const float*)d_in[1];
  const int* epoch  = (const int*)d_in[2];
  const int* max_ep = (const int*)d_in[3];
  float* out = (float*)d_out;
  float* ws  = (float*)d_ws;

  if (ws_size >= 600000) {
    unsigned int* cnt = (unsigned int*)((char*)d_ws + 4160);
    hipMemsetAsync(cnt, 0, 4, stream);
    prep_kernel<<<dim3(256), dim3(256), 0, stream>>>(pred, gt, ws);
    sink_kernel<<<dim3(16), dim3(256), 0, stream>>>(ws, epoch, max_ep, out, cnt);
  } else {
    unsigned int* cnt = (unsigned int*)((char*)d_ws + 384);
    hipMemsetAsync(cnt, 0, 4, stream);
    fused_fallback<<<dim3(16), dim3(256), 0, stream>>>(pred, gt, ws, epoch,
                                                       max_ep, out, cnt);
  }
}

// Round 8
// 103.866 us; speedup vs baseline: 3.0002x; 1.0734x over previous
//
#include <hip/hip_runtime.h>
#include <math.h>

// ---------------------------------------------------------------------------
// CurriculumLoss: l_count + t*(OT via Sinkhorn on 64x64 downsample) + t*TV
//
// K = exp(-M/0.05) underflows to 0 in f32 for M >= 8; the surviving 9-tap
// kernel is exactly separable: (1, e^-20) (x) (1, e^-20). Sinkhorn becomes
// 100 half-steps of a separable 3x3 stencil + rcp on a 64x64 field.
//
// R8: TRANSPOSED LANE LAYOUT. lane = row (64 lanes), wave w of 4 owns a
// 16-column slice held in registers.
//  - Horizontal 3-tap: in-register (column neighbors are adjacent array
//    elements); only the 2 seam columns per wave cross waves -> 2 ds_write_b32
//    + 2 ds_read_b32 per half-step (R7 needed 12 windowed row reads).
//  - Vertical 3-tap: whole-wave DPP wave_shr:1 / wave_shl:1 (full-rate VALU;
//    bound_ctrl 0-fill == zero rows -1/64).
//  - 2 barriers/iter remain, but the chain is now: barrier -> seam b32 read
//    (hidden by 14 interior columns) -> write -> barrier.
//  - prep_kernel (full-chip pooling+TV) and ticket finalize kept from R7.
//
// ws layout (floats):
//   [0..256) pc partials   [256..512) gc partials
//   [512..768) tvx         [768..1024) tvy
//   [1024..1040) cost per image ; cnt dword at byte 4160
//   [2048..67584) pooled pred fields (16 x 4096) ; [67584..133120) gt fields
// ---------------------------------------------------------------------------

#define KW1 2.0611536224385578e-09f  // exp(-20)
#define MW2 8.4967085105831778e-18f  // 2*exp(-40)
#define RP2 72
#define PDOFF 2048
#define GDOFF 67584

// 16-lane-row DPP shifts (used by prep/fallback)
__device__ __forceinline__ float dpp_right(float x) {  // lane tx+1's value; 0 at tx==15
  return __int_as_float(__builtin_amdgcn_update_dpp(
      0, __float_as_int(x), 0x101, 0xF, 0xF, true));
}
__device__ __forceinline__ float dpp_left(float x) {
  return __int_as_float(__builtin_amdgcn_update_dpp(
      0, __float_as_int(x), 0x111, 0xF, 0xF, true));
}
// whole-wave shifts: vertical neighbors in the row-per-lane layout
__device__ __forceinline__ float wshr1(float x) {  // lane i <- lane i-1; 0 into lane 0
  return __int_as_float(__builtin_amdgcn_update_dpp(
      0, __float_as_int(x), 0x138, 0xF, 0xF, true));  // wave_shr:1
}
__device__ __forceinline__ float wshl1(float x) {  // lane i <- lane i+1; 0 into lane 63
  return __int_as_float(__builtin_amdgcn_update_dpp(
      0, __float_as_int(x), 0x130, 0xF, 0xF, true));  // wave_shl:1
}

__device__ __forceinline__ float ad4(const float4 a, const float4 b) {
  return fabsf(a.x - b.x) + fabsf(a.y - b.y) + fabsf(a.z - b.z) + fabsf(a.w - b.w);
}
__device__ __forceinline__ float agent_ld(const float* p) {
  return __hip_atomic_load(p, __ATOMIC_RELAXED, __HIP_MEMORY_SCOPE_AGENT);
}

// ======================= prep: full-chip pooling + TV =======================
__global__ __launch_bounds__(256) void prep_kernel(
    const float* __restrict__ pred, const float* __restrict__ gt,
    float* __restrict__ ws) {
  __shared__ float rbuf[16];
  const int g = blockIdx.x;
  const int im = g >> 4, band = g & 15;
  const int t = threadIdx.x;
  const int ppy = t >> 6, ppx = t & 63;
  const float* pb = pred + im * 65536;
  const float* gb = gt + im * 65536;
  const int sr0 = band * 16 + ppy * 4;
  const int c0 = ppx * 4;

  float4 q[4];
  float ps = 0.f, gs = 0.f, sx = 0.f, sy = 0.f;
#pragma unroll
  for (int r = 0; r < 4; ++r) {
    q[r] = *(const float4*)(pb + (sr0 + r) * 256 + c0);
    const float4 e = *(const float4*)(gb + (sr0 + r) * 256 + c0);
    ps += (q[r].x + q[r].y) + (q[r].z + q[r].w);
    gs += (e.x + e.y) + (e.z + e.w);
    sx += fabsf(q[r].y - q[r].x) + fabsf(q[r].z - q[r].y) + fabsf(q[r].w - q[r].z);
    const float nf = __shfl_down(q[r].x, 1);
    if (ppx < 63) sx += fabsf(nf - q[r].w);
  }
  sy += ad4(q[1], q[0]) + ad4(q[2], q[1]) + ad4(q[3], q[2]);
  if (sr0 + 4 < 256) {
    const float4 qn = *(const float4*)(pb + (sr0 + 4) * 256 + c0);
    sy += ad4(qn, q[3]);
  }
  const int prow = band * 4 + ppy;
  ws[PDOFF + im * 4096 + prow * 64 + ppx] = fmaxf(ps * 0.0625f, 0.f);
  ws[GDOFF + im * 4096 + prow * 64 + ppx] = fmaxf(gs * 0.0625f, 0.f);

  float r0 = ps, r1 = gs, r2 = sx, r3 = sy;
#pragma unroll
  for (int o = 32; o > 0; o >>= 1) {
    r0 += __shfl_down(r0, o); r1 += __shfl_down(r1, o);
    r2 += __shfl_down(r2, o); r3 += __shfl_down(r3, o);
  }
  if ((t & 63) == 0) {
    const int w = t >> 6;
    rbuf[w * 4 + 0] = r0; rbuf[w * 4 + 1] = r1;
    rbuf[w * 4 + 2] = r2; rbuf[w * 4 + 3] = r3;
  }
  __syncthreads();
  if (t == 0) {
    float a0 = 0, a1 = 0, a2 = 0, a3 = 0;
    for (int w = 0; w < 4; ++w) {
      a0 += rbuf[w * 4]; a1 += rbuf[w * 4 + 1];
      a2 += rbuf[w * 4 + 2]; a3 += rbuf[w * 4 + 3];
    }
    ws[g] = a0; ws[256 + g] = a1; ws[512 + g] = a2; ws[768 + g] = a3;
  }
}

// ======================= sinkhorn: row-per-lane layout ======================
__global__ __launch_bounds__(256) void sink_kernel(
    float* __restrict__ ws, const int* __restrict__ epoch,
    const int* __restrict__ max_epoch, float* __restrict__ out,
    unsigned int* __restrict__ cnt) {
  // seam arrays: slot s in 0..5 (slot 0 and 5 = zero guards), own slot = w+1
  __shared__ float SuL[6 * 64], SuR[6 * 64], SvL[6 * 64], SvR[6 * 64];
  __shared__ float rbuf[24];
  __shared__ int lastflag;

  const int b = blockIdx.x;
  const int t = threadIdx.x;
  const int w = t >> 6;   // wave = 16-column slice
  const int l = t & 63;   // lane = row

  for (int i = t; i < 6 * 64; i += 256) {
    SuL[i] = 0.f; SuR[i] = 0.f; SvL[i] = 0.f; SvR[i] = 0.f;
  }
  __syncthreads();  // guards zeroed before anyone writes own slots
  SvL[(w + 1) * 64 + l] = 1.f;  // v init = ones seams
  SvR[(w + 1) * 64 + l] = 1.f;

  // load pooled fields: my row l, cols w*16..w*16+15 (L2-hot from prep)
  float av[16], bv[16];
  {
    const float* P = &ws[PDOFF + b * 4096 + l * 64 + w * 16];
    const float* G = &ws[GDOFF + b * 4096 + l * 64 + w * 16];
    float spd = 0.f, sgd = 0.f;
#pragma unroll
    for (int c4 = 0; c4 < 4; ++c4) {
      const float4 qa = *(const float4*)(P + 4 * c4);
      av[4 * c4] = qa.x; av[4 * c4 + 1] = qa.y;
      av[4 * c4 + 2] = qa.z; av[4 * c4 + 3] = qa.w;
      spd += (qa.x + qa.y) + (qa.z + qa.w);
      const float4 qb = *(const float4*)(G + 4 * c4);
      bv[4 * c4] = qb.x; bv[4 * c4 + 1] = qb.y;
      bv[4 * c4 + 2] = qb.z; bv[4 * c4 + 3] = qb.w;
      sgd += (qb.x + qb.y) + (qb.z + qb.w);
    }
#pragma unroll
    for (int o = 32; o > 0; o >>= 1) {
      spd += __shfl_down(spd, o); sgd += __shfl_down(sgd, o);
    }
    if (l == 0) { rbuf[w * 2] = spd; rbuf[w * 2 + 1] = sgd; }
  }
  __syncthreads();
  const float Sp = rbuf[0] + rbuf[2] + rbuf[4] + rbuf[6];
  const float Sg = rbuf[1] + rbuf[3] + rbuf[5] + rbuf[7];
#pragma unroll
  for (int c = 0; c < 16; ++c) {
    av[c] = (Sp > 0.f) ? (av[c] / Sp) : (1.f / 4096.f);
    bv[c] = (Sg > 0.f) ? (bv[c] / Sg) : (1.f / 4096.f);
  }

  const int rdL = w * 64 + l;        // left nbr's right seam (slot 0 = zeros)
  const int rdR = (w + 2) * 64 + l;  // right nbr's left seam (slot 5 = zeros)
  const int wr  = (w + 1) * 64 + l;

  float uu[16], vv[16], hh[16];
#pragma unroll
  for (int c = 0; c < 16; ++c) vv[c] = 1.f;
  __syncthreads();  // seam ones visible

#pragma unroll 1
  for (int it = 0; it < 50; ++it) {
    {  // u = a / (K v)
      const float xl = SvR[rdL];
      const float xr = SvL[rdR];
      hh[0] = fmaf(KW1, xl + vv[1], vv[0]);
#pragma unroll
      for (int c = 1; c < 15; ++c) hh[c] = fmaf(KW1, vv[c - 1] + vv[c + 1], vv[c]);
      hh[15] = fmaf(KW1, vv[14] + xr, vv[15]);
#pragma unroll
      for (int c = 0; c < 16; ++c) {
        const float up = wshr1(hh[c]);
        const float dn = wshl1(hh[c]);
        uu[c] = av[c] * __builtin_amdgcn_rcpf(fmaf(KW1, up + dn, hh[c]));
      }
      SuL[wr] = uu[0]; SuR[wr] = uu[15];
    }
    __syncthreads();
    {  // v = b / (K u)
      const float xl = SuR[rdL];
      const float xr = SuL[rdR];
      hh[0] = fmaf(KW1, xl + uu[1], uu[0]);
#pragma unroll
      for (int c = 1; c < 15; ++c) hh[c] = fmaf(KW1, uu[c - 1] + uu[c + 1], uu[c]);
      hh[15] = fmaf(KW1, uu[14] + xr, uu[15]);
#pragma unroll
      for (int c = 0; c < 16; ++c) {
        const float up = wshr1(hh[c]);
        const float dn = wshl1(hh[c]);
        vv[c] = bv[c] * __builtin_amdgcn_rcpf(fmaf(KW1, up + dn, hh[c]));
      }
      SvL[wr] = vv[0]; SvR[wr] = vv[15];
    }
    __syncthreads();
  }

  // ---- cost = sum u * ((K.M) v): edges KW1, corners 2e^-40 ----
  float c = 0.f;
  {
    const float xl = SvR[rdL];  // final v seams (barrier above)
    const float xr = SvL[rdR];
#pragma unroll
    for (int cc = 0; cc < 16; ++cc) {
      const float vl = (cc == 0) ? xl : vv[cc - 1];
      const float vr = (cc == 15) ? xr : vv[cc + 1];
      const float s = vl + vr;                       // horizontal pair
      const float e = (wshr1(vv[cc]) + wshl1(vv[cc])) + s;
      const float d = wshr1(s) + wshl1(s);           // 4 corners
      c += uu[cc] * fmaf(MW2, d, KW1 * e);
    }
  }
#pragma unroll
  for (int o = 32; o > 0; o >>= 1) c += __shfl_down(c, o);
  if (l == 0) rbuf[8 + w] = c;
  __syncthreads();
  if (t == 0) {
    ws[1024 + b] = rbuf[8] + rbuf[9] + rbuf[10] + rbuf[11];
    __threadfence();
    const unsigned int old = atomicAdd(cnt, 1u);
    lastflag = (old == 15u) ? 1 : 0;
  }
  __syncthreads();

  // ---- cooperative finalize by the last block ----
  if (lastflag) {
    __threadfence();
    float myPc = agent_ld(&ws[t]);
    float myGc = agent_ld(&ws[256 + t]);
    float myTx = agent_ld(&ws[512 + t]);
    float myTy = agent_ld(&ws[768 + t]);
#pragma unroll
    for (int o = 8; o > 0; o >>= 1) {
      myPc += __shfl_down(myPc, o, 16);
      myGc += __shfl_down(myGc, o, 16);
    }
    float d = ((t & 15) == 0) ? fabsf(myPc - myGc) : 0.f;
    float ct = (t < 16) ? agent_ld(&ws[1024 + t]) : 0.f;
#pragma unroll
    for (int o = 32; o > 0; o >>= 1) {
      d += __shfl_down(d, o); ct += __shfl_down(ct, o);
      myTx += __shfl_down(myTx, o); myTy += __shfl_down(myTy, o);
    }
    if ((t & 63) == 0) {
      const int ww = t >> 6;
      rbuf[ww * 4] = d; rbuf[ww * 4 + 1] = ct;
      rbuf[ww * 4 + 2] = myTx; rbuf[ww * 4 + 3] = myTy;
    }
    __syncthreads();
    if (t == 0) {
      float lc = 0, lot = 0, tvx = 0, tvy = 0;
      for (int ww = 0; ww < 4; ++ww) {
        lc += rbuf[ww * 4]; lot += rbuf[ww * 4 + 1];
        tvx += rbuf[ww * 4 + 2]; tvy += rbuf[ww * 4 + 3];
      }
      int me = max_epoch[0]; if (me < 1) me = 1;
      const float tt = (float)epoch[0] / (float)me;
      const float ltv = tvx / (16.f * 256.f * 255.f) + tvy / (16.f * 255.f * 256.f);
      out[0] = lc * (1.f / 16.f) + tt * (lot * (1.f / 16.f)) + tt * ltv;
    }
  }
}

// ================= fallback (R6 monolith) if ws is too small ================
#define SPW1 2.0611536224385578e-09f
__device__ __forceinline__ void hrow4(const float f[4], float h[4]) {
  const float l = dpp_left(f[3]);
  const float r = dpp_right(f[0]);
  h[0] = fmaf(KW1, l + f[1], f[0]);
  h[1] = fmaf(KW1, f[0] + f[2], f[1]);
  h[2] = fmaf(KW1, f[1] + f[3], f[2]);
  h[3] = fmaf(KW1, f[2] + r, f[3]);
}
__device__ __forceinline__ void phase_core(
    const float prev[4][4], float ph[4][4],
    const float cf0[4], const float cf3[4],
    float2 mA, float4 mB, float2 mC, float2 pA, float4 pB, float2 pC,
    float* __restrict__ RT_wr, float* __restrict__ RB_wr, int wb,
    float out0[4], float out3[4]) {
  hrow4(prev[0], ph[0]); hrow4(prev[1], ph[1]);
  hrow4(prev[2], ph[2]); hrow4(prev[3], ph[3]);
  float hm[4], hp[4];
  hm[0] = fmaf(KW1, mA.y + mB.y, mB.x);
  hm[1] = fmaf(KW1, mB.x + mB.z, mB.y);
  hm[2] = fmaf(KW1, mB.y + mB.w, mB.z);
  hm[3] = fmaf(KW1, mB.z + mC.x, mB.w);
  hp[0] = fmaf(KW1, pA.y + pB.y, pB.x);
  hp[1] = fmaf(KW1, pB.x + pB.z, pB.y);
  hp[2] = fmaf(KW1, pB.y + pB.w, pB.z);
  hp[3] = fmaf(KW1, pB.z + pC.x, pB.w);
#pragma unroll
  for (int j = 0; j < 4; ++j)
    out0[j] = cf0[j] * __builtin_amdgcn_rcpf(fmaf(KW1, hm[j] + ph[1][j], ph[0][j]));
#pragma unroll
  for (int j = 0; j < 4; ++j)
    out3[j] = cf3[j] * __builtin_amdgcn_rcpf(fmaf(KW1, ph[2][j] + hp[j], ph[3][j]));
  *(float4*)&RT_wr[wb] = make_float4(out0[0], out0[1], out0[2], out0[3]);
  *(float4*)&RB_wr[wb] = make_float4(out3[0], out3[1], out3[2], out3[3]);
}

__global__ __launch_bounds__(256) void fused_fallback(
    const float* __restrict__ pred, const float* __restrict__ gt,
    float* __restrict__ ws, const int* __restrict__ epoch,
    const int* __restrict__ max_epoch, float* __restrict__ out,
    unsigned int* __restrict__ cnt) {
  __shared__ float RTu[18 * RP2], RBu[18 * RP2];
  __shared__ float RTv[18 * RP2], RBv[18 * RP2];
  __shared__ float rbuf[24];

  const int b = blockIdx.x;
  const int t = threadIdx.x;
  const int tyg = t >> 4, tx = t & 15;
  const int y0 = tyg * 4, x0 = tx * 4;

  for (int i = t; i < 18 * RP2; i += 256) {
    RTu[i] = 0.f; RBu[i] = 0.f; RTv[i] = 0.f; RBv[i] = 0.f;
  }

  const float* pb = pred + b * 65536;
  const float* gb = gt + b * 65536;
  const int sr0 = 4 * y0, sc0 = 4 * x0;

  float pd[4][4], gd[4][4];
  float4 pr0, pr1, pr2, pr3;
  float spraw = 0.f, sgraw = 0.f, sx = 0.f, sy = 0.f;
#pragma unroll
  for (int i = 0; i < 4; ++i) {
    float a0 = 0.f, a1 = 0.f, a2 = 0.f, a3 = 0.f;
    float c0 = 0.f, c1 = 0.f, c2 = 0.f, c3 = 0.f;
#pragma unroll 1
    for (int rr = 0; rr < 4; ++rr) {
      const int r = i * 4 + rr;
      const float* prow = pb + (sr0 + r) * 256 + sc0;
      const float4 q0 = *(const float4*)(prow);
      const float4 q1 = *(const float4*)(prow + 4);
      const float4 q2 = *(const float4*)(prow + 8);
      const float4 q3 = *(const float4*)(prow + 12);
      const float s0 = (q0.x + q0.y) + (q0.z + q0.w);
      const float s1 = (q1.x + q1.y) + (q1.z + q1.w);
      const float s2 = (q2.x + q2.y) + (q2.z + q2.w);
      const float s3 = (q3.x + q3.y) + (q3.z + q3.w);
      a0 += s0; a1 += s1; a2 += s2; a3 += s3;
      spraw += (s0 + s1) + (s2 + s3);
      sx += fabsf(q0.y - q0.x) + fabsf(q0.z - q0.y) + fabsf(q0.w - q0.z)
          + fabsf(q1.x - q0.w)
          + fabsf(q1.y - q1.x) + fabsf(q1.z - q1.y) + fabsf(q1.w - q1.z)
          + fabsf(q2.x - q1.w)
          + fabsf(q2.y - q2.x) + fabsf(q2.z - q2.y) + fabsf(q2.w - q2.z)
          + fabsf(q3.x - q2.w)
          + fabsf(q3.y - q3.x) + fabsf(q3.z - q3.y) + fabsf(q3.w - q3.z);
      const float nf = dpp_right(q0.x);
      if (tx < 15) sx += fabsf(nf - q3.w);
      if (r > 0) sy += ad4(q0, pr0) + ad4(q1, pr1) + ad4(q2, pr2) + ad4(q3, pr3);
      pr0 = q0; pr1 = q1; pr2 = q2; pr3 = q3;
      const float* grow = gb + (sr0 + r) * 256 + sc0;
      const float4 g0 = *(const float4*)(grow);
      const float4 g1 = *(const float4*)(grow + 4);
      const float4 g2 = *(const float4*)(grow + 8);
      const float4 g3 = *(const float4*)(grow + 12);
      const float u0 = (g0.x + g0.y) + (g0.z + g0.w);
      const float u1 = (g1.x + g1.y) + (g1.z + g1.w);
      const float u2 = (g2.x + g2.y) + (g2.z + g2.w);
      const float u3 = (g3.x + g3.y) + (g3.z + g3.w);
      c0 += u0; c1 += u1; c2 += u2; c3 += u3;
      sgraw += (u0 + u1) + (u2 + u3);
    }
    pd[i][0] = a0; pd[i][1] = a1; pd[i][2] = a2; pd[i][3] = a3;
    gd[i][0] = c0; gd[i][1] = c1; gd[i][2] = c2; gd[i][3] = c3;
  }
  if (tyg < 15) {
    const float* prow = pb + (sr0 + 16) * 256 + sc0;
    sy += ad4(*(const float4*)(prow), pr0) + ad4(*(const float4*)(prow + 4), pr1)
        + ad4(*(const float4*)(prow + 8), pr2) + ad4(*(const float4*)(prow + 12), pr3);
  }

  float spd = 0.f, sgd = 0.f;
#pragma unroll
  for (int i = 0; i < 4; ++i)
#pragma unroll
    for (int j = 0; j < 4; ++j) {
      pd[i][j] = fmaxf(pd[i][j] * 0.0625f, 0.f); spd += pd[i][j];
      gd[i][j] = fmaxf(gd[i][j] * 0.0625f, 0.f); sgd += gd[i][j];
    }

  float r0 = spraw, r1 = sgraw, r2 = spd, r3 = sgd, r4 = sx, r5 = sy;
#pragma unroll
  for (int o = 32; o > 0; o >>= 1) {
    r0 += __shfl_down(r0, o); r1 += __shfl_down(r1, o);
    r2 += __shfl_down(r2, o); r3 += __shfl_down(r3, o);
    r4 += __shfl_down(r4, o); r5 += __shfl_down(r5, o);
  }
  if ((t & 63) == 0) {
    const int w = t >> 6;
    rbuf[w * 6 + 0] = r0; rbuf[w * 6 + 1] = r1; rbuf[w * 6 + 2] = r2;
    rbuf[w * 6 + 3] = r3; rbuf[w * 6 + 4] = r4; rbuf[w * 6 + 5] = r5;
  }
  __syncthreads();
  if (t == 0) {
    float a0 = 0, a1 = 0, a2 = 0, a3 = 0, a4 = 0, a5 = 0;
    for (int w = 0; w < 4; ++w) {
      a0 += rbuf[w * 6 + 0]; a1 += rbuf[w * 6 + 1]; a2 += rbuf[w * 6 + 2];
      a3 += rbuf[w * 6 + 3]; a4 += rbuf[w * 6 + 4]; a5 += rbuf[w * 6 + 5];
    }
    ws[b] = a0; ws[16 + b] = a1; ws[48 + b] = a4; ws[64 + b] = a5;
    rbuf[0] = a2; rbuf[1] = a3;
  }
  __syncthreads();
  const float Sp = rbuf[0], Sg = rbuf[1];

  float av[4][4], bv[4][4];
#pragma unroll
  for (int i = 0; i < 4; ++i)
#pragma unroll
    for (int j = 0; j < 4; ++j) {
      av[i][j] = (Sp > 0.f) ? (pd[i][j] / Sp) : (1.f / 4096.f);
      bv[i][j] = (Sg > 0.f) ? (gd[i][j] / Sg) : (1.f / 4096.f);
    }

  const int rbb = tyg * RP2 + x0 + 2;
  const int rtb = (tyg + 2) * RP2 + x0 + 2;
  const int wb  = (1 + tyg) * RP2 + 4 + x0;

  float uu[4][4], vv[4][4], uh[4][4], vh[4][4];
#pragma unroll
  for (int i = 0; i < 4; ++i)
#pragma unroll
    for (int j = 0; j < 4; ++j) vv[i][j] = 1.f;
  *(float4*)&RTv[wb] = make_float4(1.f, 1.f, 1.f, 1.f);
  *(float4*)&RBv[wb] = make_float4(1.f, 1.f, 1.f, 1.f);
  __syncthreads();

#pragma unroll 1
  for (int it = 0; it < 50; ++it) {
    {
      const float2 mA = *(const float2*)&RBv[rbb];
      const float4 mB = *(const float4*)&RBv[rbb + 2];
      const float2 mC = *(const float2*)&RBv[rbb + 6];
      const float2 pA = *(const float2*)&RTv[rtb];
      const float4 pB = *(const float4*)&RTv[rtb + 2];
      const float2 pC = *(const float2*)&RTv[rtb + 6];
      if (it != 0) {
#pragma unroll
        for (int j = 0; j < 4; ++j) {
          vv[1][j] = bv[1][j] * __builtin_amdgcn_rcpf(fmaf(KW1, uh[0][j] + uh[2][j], uh[1][j]));
          vv[2][j] = bv[2][j] * __builtin_amdgcn_rcpf(fmaf(KW1, uh[1][j] + uh[3][j], uh[2][j]));
        }
      }
      phase_core(vv, vh, av[0], av[3], mA, mB, mC, pA, pB, pC,
                 RTu, RBu, wb, uu[0], uu[3]);
    }
    __syncthreads();
    {
      const float2 mA = *(const float2*)&RBu[rbb];
      const float4 mB = *(const float4*)&RBu[rbb + 2];
      const float2 mC = *(const float2*)&RBu[rbb + 6];
      const float2 pA = *(const float2*)&RTu[rtb];
      const float4 pB = *(const float4*)&RTu[rtb + 2];
      const float2 pC = *(const float2*)&RTu[rtb + 6];
#pragma unroll
      for (int j = 0; j < 4; ++j) {
        uu[1][j] = av[1][j] * __builtin_amdgcn_rcpf(fmaf(KW1, vh[0][j] + vh[2][j], vh[1][j]));
        uu[2][j] = av[2][j] * __builtin_amdgcn_rcpf(fmaf(KW1, vh[1][j] + vh[3][j], vh[2][j]));
      }
      phase_core(uu, uh, bv[0], bv[3], mA, mB, mC, pA, pB, pC,
                 RTv, RBv, wb, vv[0], vv[3]);
    }
    __syncthreads();
  }
#pragma unroll
  for (int j = 0; j < 4; ++j) {
    vv[1][j] = bv[1][j] * __builtin_amdgcn_rcpf(fmaf(KW1, uh[0][j] + uh[2][j], uh[1][j]));
    vv[2][j] = bv[2][j] * __builtin_amdgcn_rcpf(fmaf(KW1, uh[1][j] + uh[3][j], uh[2][j]));
  }

  float c = 0.f;
  {
    const float2 mA = *(const float2*)&RBv[rbb];
    const float4 mB = *(const float4*)&RBv[rbb + 2];
    const float2 mC = *(const float2*)&RBv[rbb + 6];
    const float2 pA = *(const float2*)&RTv[rtb];
    const float4 pB = *(const float4*)&RTv[rtb + 2];
    const float2 pC = *(const float2*)&RTv[rtb + 6];
    float W[6][6];
    W[0][0] = mA.y; W[0][1] = mB.x; W[0][2] = mB.y;
    W[0][3] = mB.z; W[0][4] = mB.w; W[0][5] = mC.x;
    W[5][0] = pA.y; W[5][1] = pB.x; W[5][2] = pB.y;
    W[5][3] = pB.z; W[5][4] = pB.w; W[5][5] = pC.x;
#pragma unroll
    for (int i = 0; i < 4; ++i) {
      W[1 + i][0] = dpp_left(vv[i][3]);
      W[1 + i][5] = dpp_right(vv[i][0]);
#pragma unroll
      for (int j = 0; j < 4; ++j) W[1 + i][1 + j] = vv[i][j];
    }
#pragma unroll
    for (int i = 0; i < 4; ++i)
#pragma unroll
      for (int j = 0; j < 4; ++j) {
        const float e = (W[i][j + 1] + W[i + 2][j + 1])
                      + (W[i + 1][j] + W[i + 1][j + 2]);
        const float d = (W[i][j] + W[i][j + 2])
                      + (W[i + 2][j] + W[i + 2][j + 2]);
        c += uu[i][j] * fmaf(MW2, d, KW1 * e);
      }
  }
#pragma unroll
  for (int o = 32; o > 0; o >>= 1) c += __shfl_down(c, o);
  if ((t & 63) == 0) rbuf[t >> 6] = c;
  __syncthreads();
  if (t == 0) {
    ws[32 + b] = rbuf[0] + rbuf[1] + rbuf[2] + rbuf[3];
    __threadfence();
    const unsigned int old = atomicAdd(cnt, 1u);
    if (old == 15u) {
      __threadfence();
      float lc = 0.f, lot = 0.f, tvx = 0.f, tvy = 0.f;
      for (int k = 0; k < 16; ++k) {
        const float p = agent_ld(&ws[k]);
        const float g = agent_ld(&ws[16 + k]);
        const float ct = agent_ld(&ws[32 + k]);
        const float x = agent_ld(&ws[48 + k]);
        const float y = agent_ld(&ws[64 + k]);
        lc += fabsf(p - g); lot += ct; tvx += x; tvy += y;
      }
      int me = max_epoch[0]; if (me < 1) me = 1;
      const float tt = (float)epoch[0] / (float)me;
      const float ltv = tvx / (16.f * 256.f * 255.f) + tvy / (16.f * 255.f * 256.f);
      out[0] = lc * (1.f / 16.f) + tt * (lot * (1.f / 16.f)) + tt * ltv;
    }
  }
}

extern "C" void kernel_launch(void* const* d_in, const int* in_sizes, int n_in,
                              void* d_out, int out_size, void* d_ws, size_t ws_size,
                              hipStream_t stream) {
  const float* pred = (const float*)d_in[0];
  const float* gt   = (const float*)d_in[1];
  const int* epoch  = (const int*)d_in[2];
  const int* max_ep = (const int*)d_in[3];
  float* out = (float*)d_out;
  float* ws  = (float*)d_ws;

  if (ws_size >= 600000) {
    unsigned int* cnt = (unsigned int*)((char*)d_ws + 4160);
    hipMemsetAsync(cnt, 0, 4, stream);
    prep_kernel<<<dim3(256), dim3(256), 0, stream>>>(pred, gt, ws);
    sink_kernel<<<dim3(16), dim3(256), 0, stream>>>(ws, epoch, max_ep, out, cnt);
  } else {
    unsigned int* cnt = (unsigned int*)((char*)d_ws + 384);
    hipMemsetAsync(cnt, 0, 4, stream);
    fused_fallback<<<dim3(16), dim3(256), 0, stream>>>(pred, gt, ws, epoch,
                                                       max_ep, out, cnt);
  }
}